// Round 2
// baseline (3801.899 us; speedup 1.0000x reference)
//
#include <hip/hip_runtime.h>
#include <hip/hip_bf16.h>
#include <cstdint>

// ---------------- problem constants ----------------
#define BB   8
#define CC   512
#define HH   56
#define WW2  56
#define HWP  3136          // 56*56
#define WS   7
#define SS   3
#define NH   16
#define HD   32
#define TT   49            // WS*WS
#define NW   64            // (56/7)^2
#define LL   64
#define BW   512           // BB*NW
#define NTOK 25088         // BW*TT == BB*HWP

// ---------------- helpers ----------------
__device__ __forceinline__ float gelu_exact(float x) {
    return 0.5f * x * (1.0f + erff(x * 0.70710678118654752440f));
}

__device__ __forceinline__ float blk_sum256(float v, volatile float* red) {
    #pragma unroll
    for (int o = 32; o > 0; o >>= 1) v += __shfl_down(v, o, 64);
    int lane = threadIdx.x & 63, w = threadIdx.x >> 6;
    if (lane == 0) red[w] = v;
    __syncthreads();
    float s = red[0] + red[1] + red[2] + red[3];
    __syncthreads();
    return s;
}

// window row r -> (flat pixel index) under fold + roll(+3)  (also = gather source under roll(-3)+unfold)
__device__ __forceinline__ int fold_pix(int r) {
    int bw = r / TT, t = r - bw * TT;
    int b = bw >> 6, nw = bw & 63;
    int wy = nw >> 3, wx = nw & 7;
    int ty = t / WS, tx = t - ty * WS;
    int hh = wy * WS + ty + SS; if (hh >= HH) hh -= HH;
    int ww = wx * WS + tx + SS; if (ww >= WW2) ww -= WW2;
    return b * HWP + hh * WW2 + ww;
}

// ---------------- transpose: [B][HW][C] -> [B][C][HW] ----------------
__global__ __launch_bounds__(256) void k_transpose_tm2cm(const float* __restrict__ in,
                                                         float* __restrict__ out) {
    __shared__ float tile[32][33];
    int b = blockIdx.z;
    int hw0 = blockIdx.x * 32;
    int c0 = blockIdx.y * 32;
    const float* src = in + (size_t)b * CC * HWP;
    float* dst = out + (size_t)b * CC * HWP;
    for (int i = threadIdx.y; i < 32; i += 8)
        tile[i][threadIdx.x] = src[(size_t)(hw0 + i) * CC + c0 + threadIdx.x];
    __syncthreads();
    for (int i = threadIdx.y; i < 32; i += 8)
        dst[(size_t)(c0 + i) * HWP + hw0 + threadIdx.x] = tile[threadIdx.x][i];
}

// ---------------- generic fp32 GEMM ----------------
// O = act(A @ W[:, wc0:wc0+N] + bias[bc0:])  (BETA==0)
// O += A @ W[:, wc0:wc0+N]                   (BETA==1, no bias/act)
// M%64==0, N%64==0, K%16==0. Row-major.
template<int ACT, int BETA>
__global__ __launch_bounds__(256) void k_gemm(
    const float* __restrict__ A, int lda,
    const float* __restrict__ W, int ldw, int wc0,
    const float* __restrict__ bias, int bc0,
    float* __restrict__ O, int ldo, int K)
{
    __shared__ float As[16][64];
    __shared__ float Bs[16][64];
    int tid = threadIdx.x;
    int m0 = blockIdx.y * 64, n0 = blockIdx.x * 64;
    int tx = tid & 15, ty = tid >> 4;
    int arow = tid >> 2, ak = (tid & 3) << 2;
    int brow = tid >> 4, bn = (tid & 15) << 2;
    float acc[4][4] = {};
    const float* Ap = A + (size_t)(m0 + arow) * lda + ak;
    const float* Wp = W + (size_t)brow * ldw + wc0 + n0 + bn;
    for (int k0 = 0; k0 < K; k0 += 16) {
        float4 av = *(const float4*)(Ap + k0);
        float4 bv = *(const float4*)(Wp + (size_t)k0 * ldw);
        As[ak + 0][arow] = av.x;
        As[ak + 1][arow] = av.y;
        As[ak + 2][arow] = av.z;
        As[ak + 3][arow] = av.w;
        *(float4*)&Bs[brow][bn] = bv;
        __syncthreads();
        #pragma unroll
        for (int kk = 0; kk < 16; ++kk) {
            float4 a4 = *(const float4*)&As[kk][ty << 2];
            float4 b4 = *(const float4*)&Bs[kk][tx << 2];
            acc[0][0] += a4.x * b4.x; acc[0][1] += a4.x * b4.y;
            acc[0][2] += a4.x * b4.z; acc[0][3] += a4.x * b4.w;
            acc[1][0] += a4.y * b4.x; acc[1][1] += a4.y * b4.y;
            acc[1][2] += a4.y * b4.z; acc[1][3] += a4.y * b4.w;
            acc[2][0] += a4.z * b4.x; acc[2][1] += a4.z * b4.y;
            acc[2][2] += a4.z * b4.z; acc[2][3] += a4.z * b4.w;
            acc[3][0] += a4.w * b4.x; acc[3][1] += a4.w * b4.y;
            acc[3][2] += a4.w * b4.z; acc[3][3] += a4.w * b4.w;
        }
        __syncthreads();
    }
    float4 bb;
    if (BETA == 0) bb = *(const float4*)&bias[bc0 + n0 + (tx << 2)];
    #pragma unroll
    for (int u = 0; u < 4; ++u) {
        float* orow = &O[(size_t)(m0 + (ty << 2) + u) * ldo + n0 + (tx << 2)];
        float4 o;
        if (BETA == 0) {
            o.x = acc[u][0] + bb.x;
            o.y = acc[u][1] + bb.y;
            o.z = acc[u][2] + bb.z;
            o.w = acc[u][3] + bb.w;
            if (ACT == 1) {
                o.x = gelu_exact(o.x); o.y = gelu_exact(o.y);
                o.z = gelu_exact(o.z); o.w = gelu_exact(o.w);
            }
        } else {
            float4 prev = *(const float4*)orow;
            o.x = prev.x + acc[u][0];
            o.y = prev.y + acc[u][1];
            o.z = prev.z + acc[u][2];
            o.w = prev.w + acc[u][3];
        }
        *(float4*)orow = o;
    }
}

// ---------------- window gather from channel-major visual ----------------
__global__ __launch_bounds__(256) void k_gather_cm(const float* __restrict__ vis,
                                                   float* __restrict__ dst) {
    int r = blockIdx.x;
    int p = fold_pix(r);
    int b = p / HWP, hw = p - b * HWP;
    const float* src = vis + (size_t)b * CC * HWP + hw;
    float* d = dst + (size_t)r * CC;
    int c = threadIdx.x;
    d[c]       = src[(size_t)c * HWP];
    d[c + 256] = src[(size_t)(c + 256) * HWP];
}

// ---------------- window gather from token-major src ----------------
__global__ __launch_bounds__(128) void k_gather_win(const float* __restrict__ srcTM,
                                                    float* __restrict__ dst) {
    int r = blockIdx.x;
    int p = fold_pix(r);
    const float4* s4 = (const float4*)(srcTM + (size_t)p * CC);
    float4* d4 = (float4*)(dst + (size_t)r * CC);
    d4[threadIdx.x] = s4[threadIdx.x];
}

// ---------------- meta MLP relative-position bias: biasT[h][i*49+j] ----------------
__global__ __launch_bounds__(256) void k_meta(const float* __restrict__ w1,
                                              const float* __restrict__ b1,
                                              const float* __restrict__ w2,
                                              const float* __restrict__ b2,
                                              float* __restrict__ biasT) {
    int id = blockIdx.x * 256 + threadIdx.x;
    if (id >= NH * TT * TT) return;
    int h = id / (TT * TT), p = id - h * (TT * TT);
    int i = p / TT, j = p - i * TT;
    float fy = (float)(i / WS - j / WS);
    float fx = (float)(i % WS - j % WS);
    float r0 = (fy > 0.f ? 1.f : (fy < 0.f ? -1.f : 0.f)) * log1pf(fabsf(fy));
    float r1 = (fx > 0.f ? 1.f : (fx < 0.f ? -1.f : 0.f)) * log1pf(fabsf(fx));
    float acc = 0.f;
    for (int m = 0; m < 256; ++m) {
        float hv = fmaxf(r0 * w1[m] + r1 * w1[256 + m] + b1[m], 0.f);
        acc += hv * w2[m * NH + h];
    }
    biasT[id] = acc + b2[h];
}

// ---------------- window attention ----------------
__global__ __launch_bounds__(256) void k_winattn(const float* __restrict__ qkv,
                                                 const float* __restrict__ biasT,
                                                 const float* __restrict__ tau,
                                                 float* __restrict__ wout) {
    __shared__ float qs[TT * HD], ks[TT * HD], vs[TT * HD];
    __shared__ float sc[TT * TT];
    __shared__ float qn[TT], kn[TT];
    int bw = blockIdx.x, h = blockIdx.y;
    int nw = bw & 63;
    int wy = nw >> 3, wx = nw & 7;
    int tid = threadIdx.x;
    for (int idx = tid; idx < TT * HD; idx += 256) {
        int t = idx >> 5, d = idx & 31;
        size_t g = (size_t)(bw * TT + t) * 1536 + h * HD + d;
        qs[idx] = qkv[g];
        ks[idx] = qkv[g + 512];
        vs[idx] = qkv[g + 1024];
    }
    __syncthreads();
    if (tid < TT) {
        float s = 0.f, s2 = 0.f;
        for (int d = 0; d < HD; ++d) {
            float q = qs[tid * HD + d]; s += q * q;
            float k = ks[tid * HD + d]; s2 += k * k;
        }
        qn[tid] = sqrtf(s);
        kn[tid] = sqrtf(s2);
    }
    __syncthreads();
    float inv_ts = 1.0f / fmaxf(tau[h], 0.01f);
    for (int idx = tid; idx < TT * TT; idx += 256) {
        int i = idx / TT, j = idx - i * TT;
        float dot = 0.f;
        for (int d = 0; d < HD; ++d) dot += qs[i * HD + d] * ks[j * HD + d];
        float den = fmaxf(qn[i] * kn[j], 1e-6f);
        float a = dot / den * inv_ts + biasT[h * (TT * TT) + idx];
        int hi = wy * WS + i / WS, wi = wx * WS + i % WS;
        int hj = wy * WS + j / WS, wj = wx * WS + j % WS;
        int ri = (hi < 49 ? 0 : (hi < 53 ? 1 : 2)) * 3 + (wi < 49 ? 0 : (wi < 53 ? 1 : 2));
        int rj = (hj < 49 ? 0 : (hj < 53 ? 1 : 2)) * 3 + (wj < 49 ? 0 : (wj < 53 ? 1 : 2));
        if (ri != rj) a -= 100.0f;
        sc[idx] = a;
    }
    __syncthreads();
    if (tid < TT) {
        float m = -1e30f;
        for (int j = 0; j < TT; ++j) m = fmaxf(m, sc[tid * TT + j]);
        float ssum = 0.f;
        for (int j = 0; j < TT; ++j) { float e = expf(sc[tid * TT + j] - m); sc[tid * TT + j] = e; ssum += e; }
        float inv = 1.0f / ssum;
        for (int j = 0; j < TT; ++j) sc[tid * TT + j] *= inv;
    }
    __syncthreads();
    for (int idx = tid; idx < TT * HD; idx += 256) {
        int i = idx >> 5, d = idx & 31;
        float acc = 0.f;
        for (int j = 0; j < TT; ++j) acc += sc[i * TT + j] * vs[j * HD + d];
        wout[(size_t)(bw * TT + i) * CC + h * HD + d] = acc;
    }
}

// ---------------- cross attention (window bw attends to vec[bw % 8]) ----------------
__global__ __launch_bounds__(256) void k_crossattn(const float* __restrict__ q2,
                                                   const float* __restrict__ kv2,
                                                   float* __restrict__ co) {
    __shared__ float qs[TT * HD], ks[LL * HD], vs[LL * HD];
    __shared__ float sc[TT * LL];
    int bw = blockIdx.x, h = blockIdx.y;
    int bvec = bw & 7;
    int tid = threadIdx.x;
    for (int idx = tid; idx < TT * HD; idx += 256) {
        int t = idx >> 5, d = idx & 31;
        qs[idx] = q2[(size_t)(bw * TT + t) * CC + h * HD + d];
    }
    for (int idx = tid; idx < LL * HD; idx += 256) {
        int l = idx >> 5, d = idx & 31;
        size_t g = (size_t)(bvec * LL + l) * 1024 + h * HD + d;
        ks[idx] = kv2[g];
        vs[idx] = kv2[g + 512];
    }
    __syncthreads();
    const float scale = 0.17677669529663687f;  // 32^-0.5
    for (int idx = tid; idx < TT * LL; idx += 256) {
        int i = idx >> 6, j = idx & 63;
        float dot = 0.f;
        for (int d = 0; d < HD; ++d) dot += qs[i * HD + d] * ks[j * HD + d];
        sc[idx] = dot * scale;
    }
    __syncthreads();
    if (tid < TT) {
        float m = -1e30f;
        for (int j = 0; j < LL; ++j) m = fmaxf(m, sc[tid * LL + j]);
        float ssum = 0.f;
        for (int j = 0; j < LL; ++j) { float e = expf(sc[tid * LL + j] - m); sc[tid * LL + j] = e; ssum += e; }
        float inv = 1.0f / ssum;
        for (int j = 0; j < LL; ++j) sc[tid * LL + j] *= inv;
    }
    __syncthreads();
    for (int idx = tid; idx < TT * HD; idx += 256) {
        int i = idx >> 5, d = idx & 31;
        float acc = 0.f;
        for (int j = 0; j < LL; ++j) acc += sc[i * LL + j] * vs[j * HD + d];
        co[(size_t)(bw * TT + i) * CC + h * HD + d] = acc;
    }
}

// ---------------- LN1(fold(proj)) + visual(channel-major) -> skip ----------------
__global__ __launch_bounds__(256) void k_ln1_fold(const float* __restrict__ proj,
                                                  const float* __restrict__ vis,
                                                  const float* __restrict__ g,
                                                  const float* __restrict__ bta,
                                                  float* __restrict__ skip) {
    __shared__ float red[4];
    int r = blockIdx.x;
    int p = fold_pix(r);
    int b = p / HWP, hw = p - b * HWP;
    const float* row = proj + (size_t)r * CC;
    int c0 = threadIdx.x, c1 = threadIdx.x + 256;
    float x0 = row[c0], x1 = row[c1];
    float mu = blk_sum256(x0 + x1, red) * (1.f / CC);
    float d0 = x0 - mu, d1 = x1 - mu;
    float var = blk_sum256(d0 * d0 + d1 * d1, red) * (1.f / CC);
    float rstd = rsqrtf(var + 1e-5f);
    const float* vb = vis + (size_t)b * CC * HWP + hw;
    size_t o = (size_t)p * CC;
    skip[o + c0] = d0 * rstd * g[c0] + bta[c0] + vb[(size_t)c0 * HWP];
    skip[o + c1] = d1 * rstd * g[c1] + bta[c1] + vb[(size_t)c1 * HWP];
}

// ---------------- skip += LN2(fold(cout)) ----------------
__global__ __launch_bounds__(256) void k_ln2_fold_add(const float* __restrict__ cout_,
                                                      const float* __restrict__ g,
                                                      const float* __restrict__ bta,
                                                      float* __restrict__ skip) {
    __shared__ float red[4];
    int r = blockIdx.x;
    int p = fold_pix(r);
    const float* row = cout_ + (size_t)r * CC;
    int c0 = threadIdx.x, c1 = threadIdx.x + 256;
    float x0 = row[c0], x1 = row[c1];
    float mu = blk_sum256(x0 + x1, red) * (1.f / CC);
    float d0 = x0 - mu, d1 = x1 - mu;
    float var = blk_sum256(d0 * d0 + d1 * d1, red) * (1.f / CC);
    float rstd = rsqrtf(var + 1e-5f);
    size_t o = (size_t)p * CC;
    skip[o + c0] += d0 * rstd * g[c0] + bta[c0];
    skip[o + c1] += d1 * rstd * g[c1] + bta[c1];
}

// ---------------- final = skip + LN3(ff2) ----------------
__global__ __launch_bounds__(256) void k_ln3_final(const float* __restrict__ ff2,
                                                   const float* __restrict__ skip,
                                                   const float* __restrict__ g,
                                                   const float* __restrict__ bta,
                                                   float* __restrict__ fin) {
    __shared__ float red[4];
    size_t p = blockIdx.x;
    const float* row = ff2 + p * CC;
    int c0 = threadIdx.x, c1 = threadIdx.x + 256;
    float x0 = row[c0], x1 = row[c1];
    float mu = blk_sum256(x0 + x1, red) * (1.f / CC);
    float d0 = x0 - mu, d1 = x1 - mu;
    float var = blk_sum256(d0 * d0 + d1 * d1, red) * (1.f / CC);
    float rstd = rsqrtf(var + 1e-5f);
    size_t o = p * CC;
    fin[o + c0] = skip[o + c0] + d0 * rstd * g[c0] + bta[c0];
    fin[o + c1] = skip[o + c1] + d1 * rstd * g[c1] + bta[c1];
}

// ---------------- host launch ----------------
extern "C" void kernel_launch(void* const* d_in, const int* in_sizes, int n_in,
                              void* d_out, int out_size, void* d_ws, size_t ws_size,
                              hipStream_t stream) {
    const float* visual  = (const float*)d_in[0];
    const float* vector  = (const float*)d_in[1];
    const float* tm_w    = (const float*)d_in[2];
    const float* tm_b    = (const float*)d_in[3];
    const float* ln1_g   = (const float*)d_in[4];
    const float* ln1_b   = (const float*)d_in[5];
    const float* ln2_g   = (const float*)d_in[6];
    const float* ln2_b   = (const float*)d_in[7];
    const float* ln3_g   = (const float*)d_in[8];
    const float* ln3_b   = (const float*)d_in[9];
    const float* qkv_w   = (const float*)d_in[10];
    const float* qkv_b   = (const float*)d_in[11];
    const float* wproj_w = (const float*)d_in[12];
    const float* wproj_b = (const float*)d_in[13];
    const float* meta_w1 = (const float*)d_in[14];
    const float* meta_b1 = (const float*)d_in[15];
    const float* meta_w2 = (const float*)d_in[16];
    const float* meta_b2 = (const float*)d_in[17];
    const float* tau     = (const float*)d_in[18];
    const float* ca_in_w = (const float*)d_in[19];
    const float* ca_in_b = (const float*)d_in[20];
    const float* ca_out_w= (const float*)d_in[21];
    const float* ca_out_b= (const float*)d_in[22];
    const float* ff_w1   = (const float*)d_in[23];
    const float* ff_b1   = (const float*)d_in[24];
    const float* ff_w2   = (const float*)d_in[25];
    const float* ff_b2   = (const float*)d_in[26];
    float* out = (float*)d_out;

    // workspace layout (floats): 3*TOKC + small  ≈ 150 MB total
    const size_t TOKC = (size_t)NTOK * CC;   // 12,845,056
    float* ws   = (float*)d_ws;
    float* M0   = ws;                 // qkv[0:1] / proj / q2 / cout / ffh(lo) / final
    float* M1   = ws + TOKC;          // qkv[1:2] / co / ffh(hi)
    float* M2   = ws + 2 * TOKC;      // qkv[2:3] / skip (persistent from step 7)
    float* vecB  = ws + 3 * TOKC;                 // [512, 512]
    float* kv2   = vecB + (size_t)BB * LL * CC;   // [512, 1024] k|v
    float* biasT = kv2 + (size_t)512 * 1024;      // [NH, 49*49]
    float* dscr  = out;               // d_out doubles as scratch: tok / wout / pq / ff2

    // 1. vec = gelu(vector @ tm_w + tm_b)        M=512 N=512 K=256
    hipLaunchKernelGGL((k_gemm<1,0>), dim3(8, 8), dim3(256), 0, stream,
                       vector, 256, tm_w, 512, 0, tm_b, 0, vecB, 512, 256);
    // 2. tok = gather(visual, roll -3)           -> d_out
    hipLaunchKernelGGL(k_gather_cm, dim3(NTOK), dim3(256), 0, stream, visual, dscr);
    // 3. qkv = tok @ qkv_w + qkv_b               M=25088 N=1536 K=512 -> M0..M2
    hipLaunchKernelGGL((k_gemm<0,0>), dim3(24, 392), dim3(256), 0, stream,
                       dscr, 512, qkv_w, 1536, 0, qkv_b, 0, M0, 1536, 512);
    // 4. relative-position bias
    hipLaunchKernelGGL(k_meta, dim3((NH * TT * TT + 255) / 256), dim3(256), 0, stream,
                       meta_w1, meta_b1, meta_w2, meta_b2, biasT);
    // 5. window attention -> wout -> d_out
    hipLaunchKernelGGL(k_winattn, dim3(BW, NH), dim3(256), 0, stream,
                       M0, biasT, tau, dscr);
    // 6. proj = wout @ wproj_w + b               -> M0
    hipLaunchKernelGGL((k_gemm<0,0>), dim3(8, 392), dim3(256), 0, stream,
                       dscr, 512, wproj_w, 512, 0, wproj_b, 0, M0, 512, 512);
    // 7. skip = LN1(fold(proj)) + visual         -> M2
    hipLaunchKernelGGL(k_ln1_fold, dim3(NTOK), dim3(256), 0, stream,
                       M0, visual, ln1_g, ln1_b, M2);
    // 8. pq = gather(skip)                       -> d_out
    hipLaunchKernelGGL(k_gather_win, dim3(NTOK), dim3(128), 0, stream, M2, dscr);
    // 9. q2 = pq @ ca_in_w[:, :512] + bq         -> M0
    hipLaunchKernelGGL((k_gemm<0,0>), dim3(8, 392), dim3(256), 0, stream,
                       dscr, 512, ca_in_w, 1536, 0, ca_in_b, 0, M0, 512, 512);
    // 10. kv2 = vec @ ca_in_w[:, 512:1536] + b[512:]   M=512 N=1024 K=512
    hipLaunchKernelGGL((k_gemm<0,0>), dim3(16, 8), dim3(256), 0, stream,
                       vecB, 512, ca_in_w, 1536, 512, ca_in_b, 512, kv2, 1024, 512);
    // 11. cross attention -> co                  -> M1
    hipLaunchKernelGGL(k_crossattn, dim3(BW, NH), dim3(256), 0, stream,
                       M0, kv2, M1);
    // 12. cout = co @ ca_out_w + b               -> M0
    hipLaunchKernelGGL((k_gemm<0,0>), dim3(8, 392), dim3(256), 0, stream,
                       M1, 512, ca_out_w, 512, 0, ca_out_b, 0, M0, 512, 512);
    // 13. skip += LN2(fold(cout))
    hipLaunchKernelGGL(k_ln2_fold_add, dim3(NTOK), dim3(256), 0, stream,
                       M0, ln2_g, ln2_b, M2);
    // 14a. ffh_lo = gelu(skip @ ff_w1[:, :1024] + b1[:1024])   -> M0,M1
    hipLaunchKernelGGL((k_gemm<1,0>), dim3(16, 392), dim3(256), 0, stream,
                       M2, 512, ff_w1, 2048, 0, ff_b1, 0, M0, 1024, 512);
    // 14b. ff2 = ffh_lo @ ff_w2[:1024, :] + b2   -> d_out
    hipLaunchKernelGGL((k_gemm<0,0>), dim3(8, 392), dim3(256), 0, stream,
                       M0, 1024, ff_w2, 512, 0, ff_b2, 0, dscr, 512, 1024);
    // 14c. ffh_hi = gelu(skip @ ff_w1[:, 1024:] + b1[1024:])   -> M0,M1
    hipLaunchKernelGGL((k_gemm<1,0>), dim3(16, 392), dim3(256), 0, stream,
                       M2, 512, ff_w1, 2048, 1024, ff_b1, 1024, M0, 1024, 512);
    // 14d. ff2 += ffh_hi @ ff_w2[1024:, :]
    hipLaunchKernelGGL((k_gemm<0,1>), dim3(8, 392), dim3(256), 0, stream,
                       M0, 1024, ff_w2 + (size_t)1024 * 512, 512, 0, ff_b2, 0, dscr, 512, 1024);
    // 15. final = skip + LN3(ff2)                -> M0
    hipLaunchKernelGGL(k_ln3_final, dim3(NTOK), dim3(256), 0, stream,
                       dscr, M2, ln3_g, ln3_b, M0);
    // 16. final (token-major) -> d_out (channel-major)
    hipLaunchKernelGGL(k_transpose_tm2cm, dim3(HWP / 32, CC / 32, BB), dim3(256 / 8 ? 32 : 32, 8), 0, stream,
                       M0, out);
}

// Round 3
// 1855.651 us; speedup vs baseline: 2.0488x; 2.0488x over previous
//
#include <hip/hip_runtime.h>
#include <hip/hip_bf16.h>
#include <cstdint>

// ---------------- problem constants ----------------
#define BB   8
#define CC   512
#define HH   56
#define WW2  56
#define HWP  3136          // 56*56
#define WS   7
#define SS   3
#define NH   16
#define HD   32
#define TT   49            // WS*WS
#define NW   64            // (56/7)^2
#define LL   64
#define BW   512           // BB*NW
#define NTOK 25088         // BW*TT == BB*HWP

typedef __attribute__((ext_vector_type(8))) short bf16x8;
typedef __attribute__((ext_vector_type(4))) float f32x4;

// ---------------- helpers ----------------
__device__ __forceinline__ float gelu_exact(float x) {
    return 0.5f * x * (1.0f + erff(x * 0.70710678118654752440f));
}

__device__ __forceinline__ short f2bf(float v) {
    __hip_bfloat16 b = __float2bfloat16(v);
    return *reinterpret_cast<short*>(&b);
}
__device__ __forceinline__ float bf2f(short s) {
    __hip_bfloat16 b = *reinterpret_cast<__hip_bfloat16*>(&s);
    return __bfloat162float(b);
}

__device__ __forceinline__ float blk_sum256(float v, volatile float* red) {
    #pragma unroll
    for (int o = 32; o > 0; o >>= 1) v += __shfl_down(v, o, 64);
    int lane = threadIdx.x & 63, w = threadIdx.x >> 6;
    if (lane == 0) red[w] = v;
    __syncthreads();
    float s = red[0] + red[1] + red[2] + red[3];
    __syncthreads();
    return s;
}

// window row r -> flat pixel index under fold + roll(+3)
__device__ __forceinline__ int fold_pix(int r) {
    int bw = r / TT, t = r - bw * TT;
    int b = bw >> 6, nw = bw & 63;
    int wy = nw >> 3, wx = nw & 7;
    int ty = t / WS, tx = t - ty * WS;
    int hh = wy * WS + ty + SS; if (hh >= HH) hh -= HH;
    int ww = wx * WS + tx + SS; if (ww >= WW2) ww -= WW2;
    return b * HWP + hh * WW2 + ww;
}

// ---------------- transpose: [B][HW][C] -> [B][C][HW] ----------------
__global__ __launch_bounds__(256) void k_transpose_tm2cm(const float* __restrict__ in,
                                                         float* __restrict__ out) {
    __shared__ float tile[32][33];
    int b = blockIdx.z;
    int hw0 = blockIdx.x * 32;
    int c0 = blockIdx.y * 32;
    const float* src = in + (size_t)b * CC * HWP;
    float* dst = out + (size_t)b * CC * HWP;
    for (int i = threadIdx.y; i < 32; i += 8)
        tile[i][threadIdx.x] = src[(size_t)(hw0 + i) * CC + c0 + threadIdx.x];
    __syncthreads();
    for (int i = threadIdx.y; i < 32; i += 8)
        dst[(size_t)(c0 + i) * HWP + hw0 + threadIdx.x] = tile[threadIdx.x][i];
}

// ---------------- weight convert: [K][N] fp32 -> [N][K] bf16 hi/lo ----------------
__global__ __launch_bounds__(256) void k_wtcvt(const float* __restrict__ W, int K, int N,
                                               short* __restrict__ hi, short* __restrict__ lo) {
    __shared__ float tile[32][33];
    int n0 = blockIdx.x * 32, k0 = blockIdx.y * 32;
    int tx = threadIdx.x & 31, ty = threadIdx.x >> 5;
    for (int i = ty; i < 32; i += 8)
        tile[i][tx] = W[(size_t)(k0 + i) * N + n0 + tx];
    __syncthreads();
    for (int i = ty; i < 32; i += 8) {
        float v = tile[tx][i];
        short h = f2bf(v);
        short l = f2bf(v - bf2f(h));
        size_t o = (size_t)(n0 + i) * K + k0 + tx;
        hi[o] = h; lo[o] = l;
    }
}

// ---------------- MFMA split-bf16 GEMM ----------------
// O = act(A @ Bt^T + bias)  (BETA==0) ; O += A @ Bt^T  (BETA==1)
// A: [M][lda] fp32 row-major. Bt hi/lo: [N][ldk] bf16 (k contiguous).
// M%128==0, N%128==0, K%32==0. bias pre-offset to this GEMM's N range.
// LDS layout per plane: [row 0..127][kg 0..3] of 8 bf16, kg XOR-swizzled.
#define SWOFF(row, kg) ((row) * 32 + ((((kg) ^ (((row) >> 1) & 3))) << 3))
template<int ACT, int BETA>
__global__ __launch_bounds__(256) void k_mgemm(
    const float* __restrict__ A, int lda,
    const short* __restrict__ Bth, const short* __restrict__ Btl, int ldk,
    const float* __restrict__ bias,
    float* __restrict__ O, int ldo, int K)
{
    __shared__ short sAh[128 * 32], sAl[128 * 32], sBh[128 * 32], sBl[128 * 32];
    int tid = threadIdx.x;
    int m0 = blockIdx.y * 128, n0 = blockIdx.x * 128;
    int srow = tid >> 1, shalf = tid & 1;
    int w = tid >> 6, lane = tid & 63;
    int wm = w >> 1, wn = w & 1;
    int lrow = lane & 15, kg = lane >> 4;
    int wkg0 = shalf * 2;

    f32x4 acc[4][4] = {};
    const float* Ap = A + (size_t)(m0 + srow) * lda + shalf * 16;
    const short* Bhp = Bth + (size_t)(n0 + srow) * ldk + shalf * 16;
    const short* Blp = Btl + (size_t)(n0 + srow) * ldk + shalf * 16;

    for (int k0 = 0; k0 < K; k0 += 32) {
        // stage A: fp32 -> hi/lo bf16
        float av[16];
        *(float4*)&av[0]  = *(const float4*)(Ap + k0);
        *(float4*)&av[4]  = *(const float4*)(Ap + k0 + 4);
        *(float4*)&av[8]  = *(const float4*)(Ap + k0 + 8);
        *(float4*)&av[12] = *(const float4*)(Ap + k0 + 12);
        short hi[16], lo[16];
        #pragma unroll
        for (int i = 0; i < 16; ++i) {
            hi[i] = f2bf(av[i]);
            lo[i] = f2bf(av[i] - bf2f(hi[i]));
        }
        *(bf16x8*)&sAh[SWOFF(srow, wkg0)]     = *(bf16x8*)&hi[0];
        *(bf16x8*)&sAh[SWOFF(srow, wkg0 + 1)] = *(bf16x8*)&hi[8];
        *(bf16x8*)&sAl[SWOFF(srow, wkg0)]     = *(bf16x8*)&lo[0];
        *(bf16x8*)&sAl[SWOFF(srow, wkg0 + 1)] = *(bf16x8*)&lo[8];
        // stage B: copy pre-split bf16
        *(bf16x8*)&sBh[SWOFF(srow, wkg0)]     = *(const bf16x8*)(Bhp + k0);
        *(bf16x8*)&sBh[SWOFF(srow, wkg0 + 1)] = *(const bf16x8*)(Bhp + k0 + 8);
        *(bf16x8*)&sBl[SWOFF(srow, wkg0)]     = *(const bf16x8*)(Blp + k0);
        *(bf16x8*)&sBl[SWOFF(srow, wkg0 + 1)] = *(const bf16x8*)(Blp + k0 + 8);
        __syncthreads();
        // fragments
        bf16x8 fah[4], fal[4], fbh[4], fbl[4];
        #pragma unroll
        for (int mi = 0; mi < 4; ++mi) {
            int r = wm * 64 + mi * 16 + lrow;
            fah[mi] = *(bf16x8*)&sAh[SWOFF(r, kg)];
            fal[mi] = *(bf16x8*)&sAl[SWOFF(r, kg)];
        }
        #pragma unroll
        for (int ni = 0; ni < 4; ++ni) {
            int r = wn * 64 + ni * 16 + lrow;
            fbh[ni] = *(bf16x8*)&sBh[SWOFF(r, kg)];
            fbl[ni] = *(bf16x8*)&sBl[SWOFF(r, kg)];
        }
        #pragma unroll
        for (int mi = 0; mi < 4; ++mi)
            #pragma unroll
            for (int ni = 0; ni < 4; ++ni) {
                acc[mi][ni] = __builtin_amdgcn_mfma_f32_16x16x32_bf16(fah[mi], fbh[ni], acc[mi][ni], 0, 0, 0);
                acc[mi][ni] = __builtin_amdgcn_mfma_f32_16x16x32_bf16(fal[mi], fbh[ni], acc[mi][ni], 0, 0, 0);
                acc[mi][ni] = __builtin_amdgcn_mfma_f32_16x16x32_bf16(fah[mi], fbl[ni], acc[mi][ni], 0, 0, 0);
            }
        __syncthreads();
    }
    // epilogue: C layout col=lane&15, row=(lane>>4)*4+reg
    #pragma unroll
    for (int mi = 0; mi < 4; ++mi)
        #pragma unroll
        for (int ni = 0; ni < 4; ++ni) {
            int col = n0 + wn * 64 + ni * 16 + lrow;
            int rb  = m0 + wm * 64 + mi * 16 + kg * 4;
            float bv = (BETA == 0) ? bias[col] : 0.0f;
            #pragma unroll
            for (int r = 0; r < 4; ++r) {
                float* po = &O[(size_t)(rb + r) * ldo + col];
                float v = acc[mi][ni][r];
                if (BETA == 0) {
                    v += bv;
                    if (ACT == 1) v = gelu_exact(v);
                } else {
                    v += *po;
                }
                *po = v;
            }
        }
}

// ---------------- window gather from channel-major visual ----------------
__global__ __launch_bounds__(256) void k_gather_cm(const float* __restrict__ vis,
                                                   float* __restrict__ dst) {
    int r = blockIdx.x;
    int p = fold_pix(r);
    int b = p / HWP, hw = p - b * HWP;
    const float* src = vis + (size_t)b * CC * HWP + hw;
    float* d = dst + (size_t)r * CC;
    int c = threadIdx.x;
    d[c]       = src[(size_t)c * HWP];
    d[c + 256] = src[(size_t)(c + 256) * HWP];
}

// ---------------- window gather from token-major src ----------------
__global__ __launch_bounds__(128) void k_gather_win(const float* __restrict__ srcTM,
                                                    float* __restrict__ dst) {
    int r = blockIdx.x;
    int p = fold_pix(r);
    const float4* s4 = (const float4*)(srcTM + (size_t)p * CC);
    float4* d4 = (float4*)(dst + (size_t)r * CC);
    d4[threadIdx.x] = s4[threadIdx.x];
}

// ---------------- meta MLP relative-position bias: biasT[h][i*49+j] ----------------
__global__ __launch_bounds__(256) void k_meta(const float* __restrict__ w1,
                                              const float* __restrict__ b1,
                                              const float* __restrict__ w2,
                                              const float* __restrict__ b2,
                                              float* __restrict__ biasT) {
    int id = blockIdx.x * 256 + threadIdx.x;
    if (id >= NH * TT * TT) return;
    int h = id / (TT * TT), p = id - h * (TT * TT);
    int i = p / TT, j = p - i * TT;
    float fy = (float)(i / WS - j / WS);
    float fx = (float)(i % WS - j % WS);
    float r0 = (fy > 0.f ? 1.f : (fy < 0.f ? -1.f : 0.f)) * log1pf(fabsf(fy));
    float r1 = (fx > 0.f ? 1.f : (fx < 0.f ? -1.f : 0.f)) * log1pf(fabsf(fx));
    float acc = 0.f;
    for (int m = 0; m < 256; ++m) {
        float hv = fmaxf(r0 * w1[m] + r1 * w1[256 + m] + b1[m], 0.f);
        acc += hv * w2[m * NH + h];
    }
    biasT[id] = acc + b2[h];
}

// ---------------- window attention ----------------
__global__ __launch_bounds__(256) void k_winattn(const float* __restrict__ qkv,
                                                 const float* __restrict__ biasT,
                                                 const float* __restrict__ tau,
                                                 float* __restrict__ wout) {
    __shared__ float qs[TT * HD], ks[TT * HD], vs[TT * HD];
    __shared__ float sc[TT * TT];
    __shared__ float qn[TT], kn[TT];
    int bw = blockIdx.x, h = blockIdx.y;
    int nw = bw & 63;
    int wy = nw >> 3, wx = nw & 7;
    int tid = threadIdx.x;
    for (int idx = tid; idx < TT * HD; idx += 256) {
        int t = idx >> 5, d = idx & 31;
        size_t g = (size_t)(bw * TT + t) * 1536 + h * HD + d;
        qs[idx] = qkv[g];
        ks[idx] = qkv[g + 512];
        vs[idx] = qkv[g + 1024];
    }
    __syncthreads();
    if (tid < TT) {
        float s = 0.f, s2 = 0.f;
        for (int d = 0; d < HD; ++d) {
            float q = qs[tid * HD + d]; s += q * q;
            float k = ks[tid * HD + d]; s2 += k * k;
        }
        qn[tid] = sqrtf(s);
        kn[tid] = sqrtf(s2);
    }
    __syncthreads();
    float inv_ts = 1.0f / fmaxf(tau[h], 0.01f);
    for (int idx = tid; idx < TT * TT; idx += 256) {
        int i = idx / TT, j = idx - i * TT;
        float dot = 0.f;
        for (int d = 0; d < HD; ++d) dot += qs[i * HD + d] * ks[j * HD + d];
        float den = fmaxf(qn[i] * kn[j], 1e-6f);
        float a = dot / den * inv_ts + biasT[h * (TT * TT) + idx];
        int hi = wy * WS + i / WS, wi = wx * WS + i % WS;
        int hj = wy * WS + j / WS, wj = wx * WS + j % WS;
        int ri = (hi < 49 ? 0 : (hi < 53 ? 1 : 2)) * 3 + (wi < 49 ? 0 : (wi < 53 ? 1 : 2));
        int rj = (hj < 49 ? 0 : (hj < 53 ? 1 : 2)) * 3 + (wj < 49 ? 0 : (wj < 53 ? 1 : 2));
        if (ri != rj) a -= 100.0f;
        sc[idx] = a;
    }
    __syncthreads();
    if (tid < TT) {
        float m = -1e30f;
        for (int j = 0; j < TT; ++j) m = fmaxf(m, sc[tid * TT + j]);
        float ssum = 0.f;
        for (int j = 0; j < TT; ++j) { float e = expf(sc[tid * TT + j] - m); sc[tid * TT + j] = e; ssum += e; }
        float inv = 1.0f / ssum;
        for (int j = 0; j < TT; ++j) sc[tid * TT + j] *= inv;
    }
    __syncthreads();
    for (int idx = tid; idx < TT * HD; idx += 256) {
        int i = idx >> 5, d = idx & 31;
        float acc = 0.f;
        for (int j = 0; j < TT; ++j) acc += sc[i * TT + j] * vs[j * HD + d];
        wout[(size_t)(bw * TT + i) * CC + h * HD + d] = acc;
    }
}

// ---------------- cross attention (window bw attends to vec[bw % 8]) ----------------
__global__ __launch_bounds__(256) void k_crossattn(const float* __restrict__ q2,
                                                   const float* __restrict__ kv2,
                                                   float* __restrict__ co) {
    __shared__ float qs[TT * HD], ks[LL * HD], vs[LL * HD];
    __shared__ float sc[TT * LL];
    int bw = blockIdx.x, h = blockIdx.y;
    int bvec = bw & 7;
    int tid = threadIdx.x;
    for (int idx = tid; idx < TT * HD; idx += 256) {
        int t = idx >> 5, d = idx & 31;
        qs[idx] = q2[(size_t)(bw * TT + t) * CC + h * HD + d];
    }
    for (int idx = tid; idx < LL * HD; idx += 256) {
        int l = idx >> 5, d = idx & 31;
        size_t g = (size_t)(bvec * LL + l) * 1024 + h * HD + d;
        ks[idx] = kv2[g];
        vs[idx] = kv2[g + 512];
    }
    __syncthreads();
    const float scale = 0.17677669529663687f;  // 32^-0.5
    for (int idx = tid; idx < TT * LL; idx += 256) {
        int i = idx >> 6, j = idx & 63;
        float dot = 0.f;
        for (int d = 0; d < HD; ++d) dot += qs[i * HD + d] * ks[j * HD + d];
        sc[idx] = dot * scale;
    }
    __syncthreads();
    if (tid < TT) {
        float m = -1e30f;
        for (int j = 0; j < LL; ++j) m = fmaxf(m, sc[tid * LL + j]);
        float ssum = 0.f;
        for (int j = 0; j < LL; ++j) { float e = expf(sc[tid * LL + j] - m); sc[tid * LL + j] = e; ssum += e; }
        float inv = 1.0f / ssum;
        for (int j = 0; j < LL; ++j) sc[tid * LL + j] *= inv;
    }
    __syncthreads();
    for (int idx = tid; idx < TT * HD; idx += 256) {
        int i = idx >> 5, d = idx & 31;
        float acc = 0.f;
        for (int j = 0; j < LL; ++j) acc += sc[i * LL + j] * vs[j * HD + d];
        co[(size_t)(bw * TT + i) * CC + h * HD + d] = acc;
    }
}

// ---------------- LN1(fold(proj)) + visual(channel-major) -> skip ----------------
__global__ __launch_bounds__(256) void k_ln1_fold(const float* __restrict__ proj,
                                                  const float* __restrict__ vis,
                                                  const float* __restrict__ g,
                                                  const float* __restrict__ bta,
                                                  float* __restrict__ skip) {
    __shared__ float red[4];
    int r = blockIdx.x;
    int p = fold_pix(r);
    int b = p / HWP, hw = p - b * HWP;
    const float* row = proj + (size_t)r * CC;
    int c0 = threadIdx.x, c1 = threadIdx.x + 256;
    float x0 = row[c0], x1 = row[c1];
    float mu = blk_sum256(x0 + x1, red) * (1.f / CC);
    float d0 = x0 - mu, d1 = x1 - mu;
    float var = blk_sum256(d0 * d0 + d1 * d1, red) * (1.f / CC);
    float rstd = rsqrtf(var + 1e-5f);
    const float* vb = vis + (size_t)b * CC * HWP + hw;
    size_t o = (size_t)p * CC;
    skip[o + c0] = d0 * rstd * g[c0] + bta[c0] + vb[(size_t)c0 * HWP];
    skip[o + c1] = d1 * rstd * g[c1] + bta[c1] + vb[(size_t)c1 * HWP];
}

// ---------------- skip += LN2(fold(cout)) ----------------
__global__ __launch_bounds__(256) void k_ln2_fold_add(const float* __restrict__ cout_,
                                                      const float* __restrict__ g,
                                                      const float* __restrict__ bta,
                                                      float* __restrict__ skip) {
    __shared__ float red[4];
    int r = blockIdx.x;
    int p = fold_pix(r);
    const float* row = cout_ + (size_t)r * CC;
    int c0 = threadIdx.x, c1 = threadIdx.x + 256;
    float x0 = row[c0], x1 = row[c1];
    float mu = blk_sum256(x0 + x1, red) * (1.f / CC);
    float d0 = x0 - mu, d1 = x1 - mu;
    float var = blk_sum256(d0 * d0 + d1 * d1, red) * (1.f / CC);
    float rstd = rsqrtf(var + 1e-5f);
    size_t o = (size_t)p * CC;
    skip[o + c0] += d0 * rstd * g[c0] + bta[c0];
    skip[o + c1] += d1 * rstd * g[c1] + bta[c1];
}

// ---------------- final = skip + LN3(ff2) ----------------
__global__ __launch_bounds__(256) void k_ln3_final(const float* __restrict__ ff2,
                                                   const float* __restrict__ skip,
                                                   const float* __restrict__ g,
                                                   const float* __restrict__ bta,
                                                   float* __restrict__ fin) {
    __shared__ float red[4];
    size_t p = blockIdx.x;
    const float* row = ff2 + p * CC;
    int c0 = threadIdx.x, c1 = threadIdx.x + 256;
    float x0 = row[c0], x1 = row[c1];
    float mu = blk_sum256(x0 + x1, red) * (1.f / CC);
    float d0 = x0 - mu, d1 = x1 - mu;
    float var = blk_sum256(d0 * d0 + d1 * d1, red) * (1.f / CC);
    float rstd = rsqrtf(var + 1e-5f);
    size_t o = p * CC;
    fin[o + c0] = skip[o + c0] + d0 * rstd * g[c0] + bta[c0];
    fin[o + c1] = skip[o + c1] + d1 * rstd * g[c1] + bta[c1];
}

// ---------------- host launch ----------------
extern "C" void kernel_launch(void* const* d_in, const int* in_sizes, int n_in,
                              void* d_out, int out_size, void* d_ws, size_t ws_size,
                              hipStream_t stream) {
    const float* visual  = (const float*)d_in[0];
    const float* vector  = (const float*)d_in[1];
    const float* tm_w    = (const float*)d_in[2];
    const float* tm_b    = (const float*)d_in[3];
    const float* ln1_g   = (const float*)d_in[4];
    const float* ln1_b   = (const float*)d_in[5];
    const float* ln2_g   = (const float*)d_in[6];
    const float* ln2_b   = (const float*)d_in[7];
    const float* ln3_g   = (const float*)d_in[8];
    const float* ln3_b   = (const float*)d_in[9];
    const float* qkv_w   = (const float*)d_in[10];
    const float* qkv_b   = (const float*)d_in[11];
    const float* wproj_w = (const float*)d_in[12];
    const float* wproj_b = (const float*)d_in[13];
    const float* meta_w1 = (const float*)d_in[14];
    const float* meta_b1 = (const float*)d_in[15];
    const float* meta_w2 = (const float*)d_in[16];
    const float* meta_b2 = (const float*)d_in[17];
    const float* tau     = (const float*)d_in[18];
    const float* ca_in_w = (const float*)d_in[19];
    const float* ca_in_b = (const float*)d_in[20];
    const float* ca_out_w= (const float*)d_in[21];
    const float* ca_out_b= (const float*)d_in[22];
    const float* ff_w1   = (const float*)d_in[23];
    const float* ff_b1   = (const float*)d_in[24];
    const float* ff_w2   = (const float*)d_in[25];
    const float* ff_b2   = (const float*)d_in[26];
    float* out = (float*)d_out;

    // workspace layout (floats): 3*TOKC + small + weight planes  ≈ 175 MB
    const size_t TOKC = (size_t)NTOK * CC;   // 12,845,056
    float* ws   = (float*)d_ws;
    float* M0   = ws;                 // qkv[0:1] / proj / q2 / cout / ffh / final
    float* M1   = ws + TOKC;          // qkv[1:2] / co / ffh(hi)
    float* M2   = ws + 2 * TOKC;      // qkv[2:3] / skip (persistent from step 7)
    float* vecB  = ws + 3 * TOKC;                 // [512, 512]
    float* kv2   = vecB + (size_t)BB * LL * CC;   // [512, 1024] k|v
    float* biasT = kv2 + (size_t)512 * 1024;      // [NH, 49*49] = 38416
    float* dscr  = out;               // d_out doubles as scratch: tok / wout / pq / ff2

    // bf16 hi/lo transposed weight planes (shorts)
    short* WT = (short*)(biasT + 38416);
    size_t o = 0;
    short* tm_h  = WT + o; o += 131072;  short* tm_l  = WT + o; o += 131072;   // [512][256]
    short* qkv_h = WT + o; o += 786432;  short* qkv_l = WT + o; o += 786432;   // [1536][512]
    short* wpr_h = WT + o; o += 262144;  short* wpr_l = WT + o; o += 262144;   // [512][512]
    short* cai_h = WT + o; o += 786432;  short* cai_l = WT + o; o += 786432;   // [1536][512]
    short* cao_h = WT + o; o += 262144;  short* cao_l = WT + o; o += 262144;   // [512][512]
    short* ff1_h = WT + o; o += 1048576; short* ff1_l = WT + o; o += 1048576;  // [2048][512]
    short* ff2_h = WT + o; o += 1048576; short* ff2_l = WT + o; o += 1048576;  // [512][2048]

    // 0. weight conversion (transpose + bf16 hi/lo split)
    hipLaunchKernelGGL(k_wtcvt, dim3(512 / 32, 256 / 32), dim3(256), 0, stream, tm_w,    256, 512,  tm_h,  tm_l);
    hipLaunchKernelGGL(k_wtcvt, dim3(1536 / 32, 512 / 32), dim3(256), 0, stream, qkv_w,  512, 1536, qkv_h, qkv_l);
    hipLaunchKernelGGL(k_wtcvt, dim3(512 / 32, 512 / 32), dim3(256), 0, stream, wproj_w, 512, 512,  wpr_h, wpr_l);
    hipLaunchKernelGGL(k_wtcvt, dim3(1536 / 32, 512 / 32), dim3(256), 0, stream, ca_in_w,512, 1536, cai_h, cai_l);
    hipLaunchKernelGGL(k_wtcvt, dim3(512 / 32, 512 / 32), dim3(256), 0, stream, ca_out_w,512, 512,  cao_h, cao_l);
    hipLaunchKernelGGL(k_wtcvt, dim3(2048 / 32, 512 / 32), dim3(256), 0, stream, ff_w1,  512, 2048, ff1_h, ff1_l);
    hipLaunchKernelGGL(k_wtcvt, dim3(512 / 32, 2048 / 32), dim3(256), 0, stream, ff_w2,  2048, 512, ff2_h, ff2_l);

    // 1. vec = gelu(vector @ tm_w + tm_b)        M=512 N=512 K=256
    hipLaunchKernelGGL((k_mgemm<1,0>), dim3(4, 4), dim3(256), 0, stream,
                       vector, 256, tm_h, tm_l, 256, tm_b, vecB, 512, 256);
    // 2. tok = gather(visual, roll -3)           -> d_out
    hipLaunchKernelGGL(k_gather_cm, dim3(NTOK), dim3(256), 0, stream, visual, dscr);
    // 3. qkv = tok @ qkv_w + qkv_b               M=25088 N=1536 K=512 -> M0..M2
    hipLaunchKernelGGL((k_mgemm<0,0>), dim3(12, 196), dim3(256), 0, stream,
                       dscr, 512, qkv_h, qkv_l, 512, qkv_b, M0, 1536, 512);
    // 4. relative-position bias
    hipLaunchKernelGGL(k_meta, dim3((NH * TT * TT + 255) / 256), dim3(256), 0, stream,
                       meta_w1, meta_b1, meta_w2, meta_b2, biasT);
    // 5. window attention -> wout -> d_out
    hipLaunchKernelGGL(k_winattn, dim3(BW, NH), dim3(256), 0, stream,
                       M0, biasT, tau, dscr);
    // 6. proj = wout @ wproj_w + b               -> M0
    hipLaunchKernelGGL((k_mgemm<0,0>), dim3(4, 196), dim3(256), 0, stream,
                       dscr, 512, wpr_h, wpr_l, 512, wproj_b, M0, 512, 512);
    // 7. skip = LN1(fold(proj)) + visual         -> M2
    hipLaunchKernelGGL(k_ln1_fold, dim3(NTOK), dim3(256), 0, stream,
                       M0, visual, ln1_g, ln1_b, M2);
    // 8. pq = gather(skip)                       -> d_out
    hipLaunchKernelGGL(k_gather_win, dim3(NTOK), dim3(128), 0, stream, M2, dscr);
    // 9. q2 = pq @ ca_in_w[:, :512] + bq         -> M0
    hipLaunchKernelGGL((k_mgemm<0,0>), dim3(4, 196), dim3(256), 0, stream,
                       dscr, 512, cai_h, cai_l, 512, ca_in_b, M0, 512, 512);
    // 10. kv2 = vec @ ca_in_w[:, 512:1536] + b[512:]   M=512 N=1024 K=512
    hipLaunchKernelGGL((k_mgemm<0,0>), dim3(8, 4), dim3(256), 0, stream,
                       vecB, 512, cai_h + (size_t)512 * 512, cai_l + (size_t)512 * 512, 512,
                       ca_in_b + 512, kv2, 1024, 512);
    // 11. cross attention -> co                  -> M1
    hipLaunchKernelGGL(k_crossattn, dim3(BW, NH), dim3(256), 0, stream,
                       M0, kv2, M1);
    // 12. cout = co @ ca_out_w + b               -> M0
    hipLaunchKernelGGL((k_mgemm<0,0>), dim3(4, 196), dim3(256), 0, stream,
                       M1, 512, cao_h, cao_l, 512, ca_out_b, M0, 512, 512);
    // 13. skip += LN2(fold(cout))
    hipLaunchKernelGGL(k_ln2_fold_add, dim3(NTOK), dim3(256), 0, stream,
                       M0, ln2_g, ln2_b, M2);
    // 14a. ffh_lo = gelu(skip @ ff_w1[:, :1024] + b1[:1024])   -> M0,M1
    hipLaunchKernelGGL((k_mgemm<1,0>), dim3(8, 196), dim3(256), 0, stream,
                       M2, 512, ff1_h, ff1_l, 512, ff_b1, M0, 1024, 512);
    // 14b. ff2 = ffh_lo @ ff_w2[:1024, :] + b2   -> d_out
    hipLaunchKernelGGL((k_mgemm<0,0>), dim3(4, 196), dim3(256), 0, stream,
                       M0, 1024, ff2_h, ff2_l, 2048, ff_b2, dscr, 512, 1024);
    // 14c. ffh_hi = gelu(skip @ ff_w1[:, 1024:] + b1[1024:])   -> M0,M1
    hipLaunchKernelGGL((k_mgemm<1,0>), dim3(8, 196), dim3(256), 0, stream,
                       M2, 512, ff1_h + (size_t)1024 * 512, ff1_l + (size_t)1024 * 512, 512,
                       ff_b1 + 1024, M0, 1024, 512);
    // 14d. ff2 += ffh_hi @ ff_w2[1024:, :]
    hipLaunchKernelGGL((k_mgemm<0,1>), dim3(4, 196), dim3(256), 0, stream,
                       M0, 1024, ff2_h + 1024, ff2_l + 1024, 2048, ff_b2, dscr, 512, 1024);
    // 15. final = skip + LN3(ff2)                -> M0
    hipLaunchKernelGGL(k_ln3_final, dim3(NTOK), dim3(256), 0, stream,
                       dscr, M2, ln3_g, ln3_b, M0);
    // 16. final (token-major) -> d_out (channel-major)
    hipLaunchKernelGGL(k_transpose_tm2cm, dim3(HWP / 32, CC / 32, BB), dim3(32, 8), 0, stream,
                       M0, out);
}

// Round 4
// 1635.841 us; speedup vs baseline: 2.3241x; 1.1344x over previous
//
#include <hip/hip_runtime.h>
#include <hip/hip_bf16.h>
#include <cstdint>

// ---------------- problem constants ----------------
#define BB   8
#define CC   512
#define HH   56
#define WW2  56
#define HWP  3136          // 56*56
#define WS   7
#define SS   3
#define NH   16
#define HD   32
#define TT   49            // WS*WS
#define NW   64            // (56/7)^2
#define LL   64
#define BW   512           // BB*NW
#define NTOK 25088         // BW*TT == BB*HWP

typedef __attribute__((ext_vector_type(8))) short bf16x8;
typedef __attribute__((ext_vector_type(4))) float f32x4;

// ---------------- helpers ----------------
__device__ __forceinline__ float gelu_exact(float x) {
    return 0.5f * x * (1.0f + erff(x * 0.70710678118654752440f));
}

__device__ __forceinline__ short f2bf(float v) {
    __hip_bfloat16 b = __float2bfloat16(v);
    return *reinterpret_cast<short*>(&b);
}
__device__ __forceinline__ float bf2f(short s) {
    __hip_bfloat16 b = *reinterpret_cast<__hip_bfloat16*>(&s);
    return __bfloat162float(b);
}

__device__ __forceinline__ float blk_sum256(float v, volatile float* red) {
    #pragma unroll
    for (int o = 32; o > 0; o >>= 1) v += __shfl_down(v, o, 64);
    int lane = threadIdx.x & 63, w = threadIdx.x >> 6;
    if (lane == 0) red[w] = v;
    __syncthreads();
    float s = red[0] + red[1] + red[2] + red[3];
    __syncthreads();
    return s;
}

// window row r -> flat pixel index under fold + roll(+3)
__device__ __forceinline__ int fold_pix(int r) {
    int bw = r / TT, t = r - bw * TT;
    int b = bw >> 6, nw = bw & 63;
    int wy = nw >> 3, wx = nw & 7;
    int ty = t / WS, tx = t - ty * WS;
    int hh = wy * WS + ty + SS; if (hh >= HH) hh -= HH;
    int ww = wx * WS + tx + SS; if (ww >= WW2) ww -= WW2;
    return b * HWP + hh * WW2 + ww;
}

// ---------------- transpose: [B][HW][C] -> [B][C][HW] ----------------
__global__ __launch_bounds__(256) void k_transpose_tm2cm(const float* __restrict__ in,
                                                         float* __restrict__ out) {
    __shared__ float tile[32][33];
    int b = blockIdx.z;
    int hw0 = blockIdx.x * 32;
    int c0 = blockIdx.y * 32;
    const float* src = in + (size_t)b * CC * HWP;
    float* dst = out + (size_t)b * CC * HWP;
    for (int i = threadIdx.y; i < 32; i += 8)
        tile[i][threadIdx.x] = src[(size_t)(hw0 + i) * CC + c0 + threadIdx.x];
    __syncthreads();
    for (int i = threadIdx.y; i < 32; i += 8)
        dst[(size_t)(c0 + i) * HWP + hw0 + threadIdx.x] = tile[threadIdx.x][i];
}

// ---------------- weight convert: [K][N] fp32 -> [N][K] bf16 hi/lo ----------------
__global__ __launch_bounds__(256) void k_wtcvt(const float* __restrict__ W, int K, int N,
                                               short* __restrict__ hi, short* __restrict__ lo) {
    __shared__ float tile[32][33];
    int n0 = blockIdx.x * 32, k0 = blockIdx.y * 32;
    int tx = threadIdx.x & 31, ty = threadIdx.x >> 5;
    for (int i = ty; i < 32; i += 8)
        tile[i][tx] = W[(size_t)(k0 + i) * N + n0 + tx];
    __syncthreads();
    for (int i = ty; i < 32; i += 8) {
        float v = tile[tx][i];
        short h = f2bf(v);
        short l = f2bf(v - bf2f(h));
        size_t o = (size_t)(n0 + i) * K + k0 + tx;
        hi[o] = h; lo[o] = l;
    }
}

// ---------------- MFMA split-bf16 GEMM ----------------
// O = act(A @ Bt^T + bias)  (BETA==0) ; O += A @ Bt^T  (BETA==1)
// A: [M][lda] fp32 row-major. Bt hi/lo: [N][ldk] bf16 (k contiguous).
// M%128==0, N%128==0, K%32==0. bias pre-offset to this GEMM's N range.
#define SWOFF(row, kg) ((row) * 32 + ((((kg) ^ (((row) >> 1) & 3))) << 3))
template<int ACT, int BETA>
__global__ __launch_bounds__(256) void k_mgemm(
    const float* __restrict__ A, int lda,
    const short* __restrict__ Bth, const short* __restrict__ Btl, int ldk,
    const float* __restrict__ bias,
    float* __restrict__ O, int ldo, int K)
{
    __shared__ short sAh[128 * 32], sAl[128 * 32], sBh[128 * 32], sBl[128 * 32];
    int tid = threadIdx.x;
    int m0 = blockIdx.y * 128, n0 = blockIdx.x * 128;
    int srow = tid >> 1, shalf = tid & 1;
    int w = tid >> 6, lane = tid & 63;
    int wm = w >> 1, wn = w & 1;
    int lrow = lane & 15, kg = lane >> 4;
    int wkg0 = shalf * 2;

    f32x4 acc[4][4] = {};
    const float* Ap = A + (size_t)(m0 + srow) * lda + shalf * 16;
    const short* Bhp = Bth + (size_t)(n0 + srow) * ldk + shalf * 16;
    const short* Blp = Btl + (size_t)(n0 + srow) * ldk + shalf * 16;

    for (int k0 = 0; k0 < K; k0 += 32) {
        float av[16];
        *(float4*)&av[0]  = *(const float4*)(Ap + k0);
        *(float4*)&av[4]  = *(const float4*)(Ap + k0 + 4);
        *(float4*)&av[8]  = *(const float4*)(Ap + k0 + 8);
        *(float4*)&av[12] = *(const float4*)(Ap + k0 + 12);
        short hi[16], lo[16];
        #pragma unroll
        for (int i = 0; i < 16; ++i) {
            hi[i] = f2bf(av[i]);
            lo[i] = f2bf(av[i] - bf2f(hi[i]));
        }
        *(bf16x8*)&sAh[SWOFF(srow, wkg0)]     = *(bf16x8*)&hi[0];
        *(bf16x8*)&sAh[SWOFF(srow, wkg0 + 1)] = *(bf16x8*)&hi[8];
        *(bf16x8*)&sAl[SWOFF(srow, wkg0)]     = *(bf16x8*)&lo[0];
        *(bf16x8*)&sAl[SWOFF(srow, wkg0 + 1)] = *(bf16x8*)&lo[8];
        *(bf16x8*)&sBh[SWOFF(srow, wkg0)]     = *(const bf16x8*)(Bhp + k0);
        *(bf16x8*)&sBh[SWOFF(srow, wkg0 + 1)] = *(const bf16x8*)(Bhp + k0 + 8);
        *(bf16x8*)&sBl[SWOFF(srow, wkg0)]     = *(const bf16x8*)(Blp + k0);
        *(bf16x8*)&sBl[SWOFF(srow, wkg0 + 1)] = *(const bf16x8*)(Blp + k0 + 8);
        __syncthreads();
        bf16x8 fah[4], fal[4], fbh[4], fbl[4];
        #pragma unroll
        for (int mi = 0; mi < 4; ++mi) {
            int r = wm * 64 + mi * 16 + lrow;
            fah[mi] = *(bf16x8*)&sAh[SWOFF(r, kg)];
            fal[mi] = *(bf16x8*)&sAl[SWOFF(r, kg)];
        }
        #pragma unroll
        for (int ni = 0; ni < 4; ++ni) {
            int r = wn * 64 + ni * 16 + lrow;
            fbh[ni] = *(bf16x8*)&sBh[SWOFF(r, kg)];
            fbl[ni] = *(bf16x8*)&sBl[SWOFF(r, kg)];
        }
        #pragma unroll
        for (int mi = 0; mi < 4; ++mi)
            #pragma unroll
            for (int ni = 0; ni < 4; ++ni) {
                acc[mi][ni] = __builtin_amdgcn_mfma_f32_16x16x32_bf16(fah[mi], fbh[ni], acc[mi][ni], 0, 0, 0);
                acc[mi][ni] = __builtin_amdgcn_mfma_f32_16x16x32_bf16(fal[mi], fbh[ni], acc[mi][ni], 0, 0, 0);
                acc[mi][ni] = __builtin_amdgcn_mfma_f32_16x16x32_bf16(fah[mi], fbl[ni], acc[mi][ni], 0, 0, 0);
            }
        __syncthreads();
    }
    #pragma unroll
    for (int mi = 0; mi < 4; ++mi)
        #pragma unroll
        for (int ni = 0; ni < 4; ++ni) {
            int col = n0 + wn * 64 + ni * 16 + lrow;
            int rb  = m0 + wm * 64 + mi * 16 + kg * 4;
            float bv = (BETA == 0) ? bias[col] : 0.0f;
            #pragma unroll
            for (int r = 0; r < 4; ++r) {
                float* po = &O[(size_t)(rb + r) * ldo + col];
                float v = acc[mi][ni][r];
                if (BETA == 0) {
                    v += bv;
                    if (ACT == 1) v = gelu_exact(v);
                } else {
                    v += *po;
                }
                *po = v;
            }
        }
}

// ---------------- window gather from channel-major visual ----------------
__global__ __launch_bounds__(256) void k_gather_cm(const float* __restrict__ vis,
                                                   float* __restrict__ dst) {
    int r = blockIdx.x;
    int p = fold_pix(r);
    int b = p / HWP, hw = p - b * HWP;
    const float* src = vis + (size_t)b * CC * HWP + hw;
    float* d = dst + (size_t)r * CC;
    int c = threadIdx.x;
    d[c]       = src[(size_t)c * HWP];
    d[c + 256] = src[(size_t)(c + 256) * HWP];
}

// ---------------- window gather from token-major src ----------------
__global__ __launch_bounds__(128) void k_gather_win(const float* __restrict__ srcTM,
                                                    float* __restrict__ dst) {
    int r = blockIdx.x;
    int p = fold_pix(r);
    const float4* s4 = (const float4*)(srcTM + (size_t)p * CC);
    float4* d4 = (float4*)(dst + (size_t)r * CC);
    d4[threadIdx.x] = s4[threadIdx.x];
}

// ---------------- meta MLP relative-position bias: biasT[h][i*49+j] ----------------
__global__ __launch_bounds__(256) void k_meta(const float* __restrict__ w1,
                                              const float* __restrict__ b1,
                                              const float* __restrict__ w2,
                                              const float* __restrict__ b2,
                                              float* __restrict__ biasT) {
    int id = blockIdx.x * 256 + threadIdx.x;
    if (id >= NH * TT * TT) return;
    int h = id / (TT * TT), p = id - h * (TT * TT);
    int i = p / TT, j = p - i * TT;
    float fy = (float)(i / WS - j / WS);
    float fx = (float)(i % WS - j % WS);
    float r0 = (fy > 0.f ? 1.f : (fy < 0.f ? -1.f : 0.f)) * log1pf(fabsf(fy));
    float r1 = (fx > 0.f ? 1.f : (fx < 0.f ? -1.f : 0.f)) * log1pf(fabsf(fx));
    float acc = 0.f;
    for (int m = 0; m < 256; ++m) {
        float hv = fmaxf(r0 * w1[m] + r1 * w1[256 + m] + b1[m], 0.f);
        acc += hv * w2[m * NH + h];
    }
    biasT[id] = acc + b2[h];
}

// ---------------- window attention (bank-conflict-free, wave softmax) ----------------
// K stored transposed with stride 65: ks_t[d*65 + t]  (banks (d+t)&31 -> conflict-free)
__global__ __launch_bounds__(256) void k_winattn(const float* __restrict__ qkv,
                                                 const float* __restrict__ biasT,
                                                 const float* __restrict__ tau,
                                                 float* __restrict__ wout) {
    __shared__ float qs[TT * HD];       // [49][32] row-major (broadcast reads)
    __shared__ float ks_t[HD * 65];     // [32][65] transposed, padded
    __shared__ float vs[TT * HD];       // [49][32]
    __shared__ float sc[TT * 64];       // probs, padded row stride 64
    int bw = blockIdx.x, h = blockIdx.y;
    int nw = bw & 63;
    int wy = nw >> 3, wx = nw & 7;
    int tid = threadIdx.x;
    int w = tid >> 6, j = tid & 63;

    for (int idx = tid; idx < TT * HD; idx += 256) {
        int t = idx >> 5, d = idx & 31;
        size_t g = (size_t)(bw * TT + t) * 1536 + h * HD + d;
        qs[idx] = qkv[g];
        ks_t[d * 65 + t] = qkv[g + 512];
        vs[idx] = qkv[g + 1024];
    }
    // zero the pad columns t=49..64 of ks_t
    for (int idx = tid; idx < HD * 16; idx += 256) {
        int d = idx >> 4, t = TT + (idx & 15);
        ks_t[d * 65 + t] = 0.f;
    }
    __syncthreads();

    // per-lane key norm (lanes j>=49 see zeros -> kn=0, unused)
    float kk = 0.f;
    #pragma unroll
    for (int d = 0; d < HD; ++d) { float k = ks_t[d * 65 + j]; kk += k * k; }
    float kn = sqrtf(kk);
    float inv_ts = 1.0f / fmaxf(tau[h], 0.01f);
    int hj = wy * WS + (j < TT ? j / WS : 0), wj = wx * WS + (j < TT ? j % WS : 0);
    int rj = (hj < 49 ? 0 : (hj < 53 ? 1 : 2)) * 3 + (wj < 49 ? 0 : (wj < 53 ? 1 : 2));

    for (int i = w; i < TT; i += 4) {
        float dot = 0.f, qq = 0.f;
        #pragma unroll
        for (int d = 0; d < HD; ++d) {
            float q = qs[i * HD + d];          // wave-uniform broadcast
            dot += q * ks_t[d * 65 + j];       // 2-way bank alias: free
            qq  += q * q;
        }
        float a;
        if (j < TT) {
            float den = fmaxf(sqrtf(qq) * kn, 1e-6f);
            a = dot / den * inv_ts + biasT[h * (TT * TT) + i * TT + j];
            int hi = wy * WS + i / WS, wi = wx * WS + i % WS;
            int ri = (hi < 49 ? 0 : (hi < 53 ? 1 : 2)) * 3 + (wi < 49 ? 0 : (wi < 53 ? 1 : 2));
            if (ri != rj) a -= 100.0f;
        } else {
            a = -1e30f;
        }
        float m = a;
        #pragma unroll
        for (int o = 32; o > 0; o >>= 1) m = fmaxf(m, __shfl_xor(m, o, 64));
        float e = expf(a - m);
        float s = e;
        #pragma unroll
        for (int o = 32; o > 0; o >>= 1) s += __shfl_xor(s, o, 64);
        sc[i * 64 + j] = e / s;
    }
    __syncthreads();

    for (int idx = tid; idx < TT * HD; idx += 256) {
        int i = idx >> 5, d = idx & 31;
        float acc = 0.f;
        for (int jj = 0; jj < TT; ++jj) acc += sc[i * 64 + jj] * vs[jj * HD + d];
        wout[(size_t)(bw * TT + i) * CC + h * HD + d] = acc;
    }
}

// ---------------- cross attention (window bw attends to vec[bw % 8]) ----------------
__global__ __launch_bounds__(256) void k_crossattn(const float* __restrict__ q2,
                                                   const float* __restrict__ kv2,
                                                   float* __restrict__ co) {
    __shared__ float qs[TT * HD];       // [49][32]
    __shared__ float ks_t[HD * 65];     // [32][65] transposed, padded
    __shared__ float vs[LL * HD];       // [64][32]
    __shared__ float sc[TT * 64];
    int bw = blockIdx.x, h = blockIdx.y;
    int bvec = bw & 7;
    int tid = threadIdx.x;
    int w = tid >> 6, j = tid & 63;

    for (int idx = tid; idx < TT * HD; idx += 256) {
        int t = idx >> 5, d = idx & 31;
        qs[idx] = q2[(size_t)(bw * TT + t) * CC + h * HD + d];
    }
    for (int idx = tid; idx < LL * HD; idx += 256) {
        int l = idx >> 5, d = idx & 31;
        size_t g = (size_t)(bvec * LL + l) * 1024 + h * HD + d;
        ks_t[d * 65 + l] = kv2[g];
        vs[idx] = kv2[g + 512];
    }
    __syncthreads();

    const float scale = 0.17677669529663687f;  // 32^-0.5
    for (int i = w; i < TT; i += 4) {
        float dot = 0.f;
        #pragma unroll
        for (int d = 0; d < HD; ++d)
            dot += qs[i * HD + d] * ks_t[d * 65 + j];
        float a = dot * scale;
        float m = a;
        #pragma unroll
        for (int o = 32; o > 0; o >>= 1) m = fmaxf(m, __shfl_xor(m, o, 64));
        float e = expf(a - m);
        float s = e;
        #pragma unroll
        for (int o = 32; o > 0; o >>= 1) s += __shfl_xor(s, o, 64);
        sc[i * 64 + j] = e / s;
    }
    __syncthreads();

    for (int idx = tid; idx < TT * HD; idx += 256) {
        int i = idx >> 5, d = idx & 31;
        float acc = 0.f;
        for (int l = 0; l < LL; ++l) acc += sc[i * 64 + l] * vs[l * HD + d];
        co[(size_t)(bw * TT + i) * CC + h * HD + d] = acc;
    }
}

// ---------------- LN1(fold(proj)) + visual(channel-major) -> skip ----------------
__global__ __launch_bounds__(256) void k_ln1_fold(const float* __restrict__ proj,
                                                  const float* __restrict__ vis,
                                                  const float* __restrict__ g,
                                                  const float* __restrict__ bta,
                                                  float* __restrict__ skip) {
    __shared__ float red[4];
    int r = blockIdx.x;
    int p = fold_pix(r);
    int b = p / HWP, hw = p - b * HWP;
    const float* row = proj + (size_t)r * CC;
    int c0 = threadIdx.x, c1 = threadIdx.x + 256;
    float x0 = row[c0], x1 = row[c1];
    float mu = blk_sum256(x0 + x1, red) * (1.f / CC);
    float d0 = x0 - mu, d1 = x1 - mu;
    float var = blk_sum256(d0 * d0 + d1 * d1, red) * (1.f / CC);
    float rstd = rsqrtf(var + 1e-5f);
    const float* vb = vis + (size_t)b * CC * HWP + hw;
    size_t o = (size_t)p * CC;
    skip[o + c0] = d0 * rstd * g[c0] + bta[c0] + vb[(size_t)c0 * HWP];
    skip[o + c1] = d1 * rstd * g[c1] + bta[c1] + vb[(size_t)c1 * HWP];
}

// ---------------- skip += LN2(fold(cout)) ----------------
__global__ __launch_bounds__(256) void k_ln2_fold_add(const float* __restrict__ cout_,
                                                      const float* __restrict__ g,
                                                      const float* __restrict__ bta,
                                                      float* __restrict__ skip) {
    __shared__ float red[4];
    int r = blockIdx.x;
    int p = fold_pix(r);
    const float* row = cout_ + (size_t)r * CC;
    int c0 = threadIdx.x, c1 = threadIdx.x + 256;
    float x0 = row[c0], x1 = row[c1];
    float mu = blk_sum256(x0 + x1, red) * (1.f / CC);
    float d0 = x0 - mu, d1 = x1 - mu;
    float var = blk_sum256(d0 * d0 + d1 * d1, red) * (1.f / CC);
    float rstd = rsqrtf(var + 1e-5f);
    size_t o = (size_t)p * CC;
    skip[o + c0] += d0 * rstd * g[c0] + bta[c0];
    skip[o + c1] += d1 * rstd * g[c1] + bta[c1];
}

// ---------------- final = skip + LN3(ff2) ----------------
__global__ __launch_bounds__(256) void k_ln3_final(const float* __restrict__ ff2,
                                                   const float* __restrict__ skip,
                                                   const float* __restrict__ g,
                                                   const float* __restrict__ bta,
                                                   float* __restrict__ fin) {
    __shared__ float red[4];
    size_t p = blockIdx.x;
    const float* row = ff2 + p * CC;
    int c0 = threadIdx.x, c1 = threadIdx.x + 256;
    float x0 = row[c0], x1 = row[c1];
    float mu = blk_sum256(x0 + x1, red) * (1.f / CC);
    float d0 = x0 - mu, d1 = x1 - mu;
    float var = blk_sum256(d0 * d0 + d1 * d1, red) * (1.f / CC);
    float rstd = rsqrtf(var + 1e-5f);
    size_t o = p * CC;
    fin[o + c0] = skip[o + c0] + d0 * rstd * g[c0] + bta[c0];
    fin[o + c1] = skip[o + c1] + d1 * rstd * g[c1] + bta[c1];
}

// ---------------- host launch ----------------
extern "C" void kernel_launch(void* const* d_in, const int* in_sizes, int n_in,
                              void* d_out, int out_size, void* d_ws, size_t ws_size,
                              hipStream_t stream) {
    const float* visual  = (const float*)d_in[0];
    const float* vector  = (const float*)d_in[1];
    const float* tm_w    = (const float*)d_in[2];
    const float* tm_b    = (const float*)d_in[3];
    const float* ln1_g   = (const float*)d_in[4];
    const float* ln1_b   = (const float*)d_in[5];
    const float* ln2_g   = (const float*)d_in[6];
    const float* ln2_b   = (const float*)d_in[7];
    const float* ln3_g   = (const float*)d_in[8];
    const float* ln3_b   = (const float*)d_in[9];
    const float* qkv_w   = (const float*)d_in[10];
    const float* qkv_b   = (const float*)d_in[11];
    const float* wproj_w = (const float*)d_in[12];
    const float* wproj_b = (const float*)d_in[13];
    const float* meta_w1 = (const float*)d_in[14];
    const float* meta_b1 = (const float*)d_in[15];
    const float* meta_w2 = (const float*)d_in[16];
    const float* meta_b2 = (const float*)d_in[17];
    const float* tau     = (const float*)d_in[18];
    const float* ca_in_w = (const float*)d_in[19];
    const float* ca_in_b = (const float*)d_in[20];
    const float* ca_out_w= (const float*)d_in[21];
    const float* ca_out_b= (const float*)d_in[22];
    const float* ff_w1   = (const float*)d_in[23];
    const float* ff_b1   = (const float*)d_in[24];
    const float* ff_w2   = (const float*)d_in[25];
    const float* ff_b2   = (const float*)d_in[26];
    float* out = (float*)d_out;

    // workspace layout (floats): 3*TOKC + small + weight planes  ≈ 175 MB
    const size_t TOKC = (size_t)NTOK * CC;   // 12,845,056
    float* ws   = (float*)d_ws;
    float* M0   = ws;                 // qkv[0:1] / proj / q2 / cout / ffh / final
    float* M1   = ws + TOKC;          // qkv[1:2] / co / ffh(hi)
    float* M2   = ws + 2 * TOKC;      // qkv[2:3] / skip (persistent from step 7)
    float* vecB  = ws + 3 * TOKC;                 // [512, 512]
    float* kv2   = vecB + (size_t)BB * LL * CC;   // [512, 1024] k|v
    float* biasT = kv2 + (size_t)512 * 1024;      // [NH, 49*49] = 38416
    float* dscr  = out;               // d_out doubles as scratch: tok / wout / pq / ff2

    // bf16 hi/lo transposed weight planes (shorts)
    short* WT = (short*)(biasT + 38416);
    size_t o = 0;
    short* tm_h  = WT + o; o += 131072;  short* tm_l  = WT + o; o += 131072;   // [512][256]
    short* qkv_h = WT + o; o += 786432;  short* qkv_l = WT + o; o += 786432;   // [1536][512]
    short* wpr_h = WT + o; o += 262144;  short* wpr_l = WT + o; o += 262144;   // [512][512]
    short* cai_h = WT + o; o += 786432;  short* cai_l = WT + o; o += 786432;   // [1536][512]
    short* cao_h = WT + o; o += 262144;  short* cao_l = WT + o; o += 262144;   // [512][512]
    short* ff1_h = WT + o; o += 1048576; short* ff1_l = WT + o; o += 1048576;  // [2048][512]
    short* ff2_h = WT + o; o += 1048576; short* ff2_l = WT + o; o += 1048576;  // [512][2048]

    // 0. weight conversion (transpose + bf16 hi/lo split)
    hipLaunchKernelGGL(k_wtcvt, dim3(512 / 32, 256 / 32), dim3(256), 0, stream, tm_w,    256, 512,  tm_h,  tm_l);
    hipLaunchKernelGGL(k_wtcvt, dim3(1536 / 32, 512 / 32), dim3(256), 0, stream, qkv_w,  512, 1536, qkv_h, qkv_l);
    hipLaunchKernelGGL(k_wtcvt, dim3(512 / 32, 512 / 32), dim3(256), 0, stream, wproj_w, 512, 512,  wpr_h, wpr_l);
    hipLaunchKernelGGL(k_wtcvt, dim3(1536 / 32, 512 / 32), dim3(256), 0, stream, ca_in_w,512, 1536, cai_h, cai_l);
    hipLaunchKernelGGL(k_wtcvt, dim3(512 / 32, 512 / 32), dim3(256), 0, stream, ca_out_w,512, 512,  cao_h, cao_l);
    hipLaunchKernelGGL(k_wtcvt, dim3(2048 / 32, 512 / 32), dim3(256), 0, stream, ff_w1,  512, 2048, ff1_h, ff1_l);
    hipLaunchKernelGGL(k_wtcvt, dim3(512 / 32, 2048 / 32), dim3(256), 0, stream, ff_w2,  2048, 512, ff2_h, ff2_l);

    // 1. vec = gelu(vector @ tm_w + tm_b)        M=512 N=512 K=256
    hipLaunchKernelGGL((k_mgemm<1,0>), dim3(4, 4), dim3(256), 0, stream,
                       vector, 256, tm_h, tm_l, 256, tm_b, vecB, 512, 256);
    // 2. tok = gather(visual, roll -3)           -> d_out
    hipLaunchKernelGGL(k_gather_cm, dim3(NTOK), dim3(256), 0, stream, visual, dscr);
    // 3. qkv = tok @ qkv_w + qkv_b               M=25088 N=1536 K=512 -> M0..M2
    hipLaunchKernelGGL((k_mgemm<0,0>), dim3(12, 196), dim3(256), 0, stream,
                       dscr, 512, qkv_h, qkv_l, 512, qkv_b, M0, 1536, 512);
    // 4. relative-position bias
    hipLaunchKernelGGL(k_meta, dim3((NH * TT * TT + 255) / 256), dim3(256), 0, stream,
                       meta_w1, meta_b1, meta_w2, meta_b2, biasT);
    // 5. window attention -> wout -> d_out
    hipLaunchKernelGGL(k_winattn, dim3(BW, NH), dim3(256), 0, stream,
                       M0, biasT, tau, dscr);
    // 6. proj = wout @ wproj_w + b               -> M0
    hipLaunchKernelGGL((k_mgemm<0,0>), dim3(4, 196), dim3(256), 0, stream,
                       dscr, 512, wpr_h, wpr_l, 512, wproj_b, M0, 512, 512);
    // 7. skip = LN1(fold(proj)) + visual         -> M2
    hipLaunchKernelGGL(k_ln1_fold, dim3(NTOK), dim3(256), 0, stream,
                       M0, visual, ln1_g, ln1_b, M2);
    // 8. pq = gather(skip)                       -> d_out
    hipLaunchKernelGGL(k_gather_win, dim3(NTOK), dim3(128), 0, stream, M2, dscr);
    // 9. q2 = pq @ ca_in_w[:, :512] + bq         -> M0
    hipLaunchKernelGGL((k_mgemm<0,0>), dim3(4, 196), dim3(256), 0, stream,
                       dscr, 512, cai_h, cai_l, 512, ca_in_b, M0, 512, 512);
    // 10. kv2 = vec @ ca_in_w[:, 512:1536] + b[512:]   M=512 N=1024 K=512
    hipLaunchKernelGGL((k_mgemm<0,0>), dim3(8, 4), dim3(256), 0, stream,
                       vecB, 512, cai_h + (size_t)512 * 512, cai_l + (size_t)512 * 512, 512,
                       ca_in_b + 512, kv2, 1024, 512);
    // 11. cross attention -> co                  -> M1
    hipLaunchKernelGGL(k_crossattn, dim3(BW, NH), dim3(256), 0, stream,
                       M0, kv2, M1);
    // 12. cout = co @ ca_out_w + b               -> M0
    hipLaunchKernelGGL((k_mgemm<0,0>), dim3(4, 196), dim3(256), 0, stream,
                       M1, 512, cao_h, cao_l, 512, ca_out_b, M0, 512, 512);
    // 13. skip += LN2(fold(cout))
    hipLaunchKernelGGL(k_ln2_fold_add, dim3(NTOK), dim3(256), 0, stream,
                       M0, ln2_g, ln2_b, M2);
    // 14a. ffh_lo = gelu(skip @ ff_w1[:, :1024] + b1[:1024])   -> M0,M1
    hipLaunchKernelGGL((k_mgemm<1,0>), dim3(8, 196), dim3(256), 0, stream,
                       M2, 512, ff1_h, ff1_l, 512, ff_b1, M0, 1024, 512);
    // 14b. ff2 = ffh_lo @ ff_w2[:1024, :] + b2   -> d_out
    hipLaunchKernelGGL((k_mgemm<0,0>), dim3(4, 196), dim3(256), 0, stream,
                       M0, 1024, ff2_h, ff2_l, 2048, ff_b2, dscr, 512, 1024);
    // 14c. ffh_hi = gelu(skip @ ff_w1[:, 1024:] + b1[1024:])   -> M0,M1
    hipLaunchKernelGGL((k_mgemm<1,0>), dim3(8, 196), dim3(256), 0, stream,
                       M2, 512, ff1_h + (size_t)1024 * 512, ff1_l + (size_t)1024 * 512, 512,
                       ff_b1 + 1024, M0, 1024, 512);
    // 14d. ff2 += ffh_hi @ ff_w2[1024:, :]
    hipLaunchKernelGGL((k_mgemm<0,1>), dim3(4, 196), dim3(256), 0, stream,
                       M0, 1024, ff2_h + 1024, ff2_l + 1024, 2048, ff_b2, dscr, 512, 1024);
    // 15. final = skip + LN3(ff2)                -> M0
    hipLaunchKernelGGL(k_ln3_final, dim3(NTOK), dim3(256), 0, stream,
                       dscr, M2, ln3_g, ln3_b, M0);
    // 16. final (token-major) -> d_out (channel-major)
    hipLaunchKernelGGL(k_transpose_tm2cm, dim3(HWP / 32, CC / 32, BB), dim3(32, 8), 0, stream,
                       M0, out);
}

// Round 5
// 1373.488 us; speedup vs baseline: 2.7681x; 1.1910x over previous
//
#include <hip/hip_runtime.h>
#include <hip/hip_bf16.h>
#include <cstdint>

// ---------------- problem constants ----------------
#define BB   8
#define CC   512
#define HH   56
#define WW2  56
#define HWP  3136          // 56*56
#define WS   7
#define SS   3
#define NH   16
#define HD   32
#define TT   49            // WS*WS
#define NW   64            // (56/7)^2
#define LL   64
#define BW   512           // BB*NW
#define NTOK 25088         // BW*TT == BB*HWP

typedef __attribute__((ext_vector_type(8))) short bf16x8;
typedef __attribute__((ext_vector_type(4))) float f32x4;

// ---------------- helpers ----------------
__device__ __forceinline__ float gelu_exact(float x) {
    return 0.5f * x * (1.0f + erff(x * 0.70710678118654752440f));
}
__device__ __forceinline__ short f2bf(float v) {
    __hip_bfloat16 b = __float2bfloat16(v);
    return *reinterpret_cast<short*>(&b);
}
__device__ __forceinline__ float bf2f(short s) {
    __hip_bfloat16 b = *reinterpret_cast<__hip_bfloat16*>(&s);
    return __bfloat162float(b);
}
__device__ __forceinline__ void gl_lds16(const void* g, void* l) {
    __builtin_amdgcn_global_load_lds(
        (const __attribute__((address_space(1))) void*)g,
        (__attribute__((address_space(3))) void*)l, 16, 0, 0);
}

__device__ __forceinline__ float blk_sum256(float v, volatile float* red) {
    #pragma unroll
    for (int o = 32; o > 0; o >>= 1) v += __shfl_down(v, o, 64);
    int lane = threadIdx.x & 63, w = threadIdx.x >> 6;
    if (lane == 0) red[w] = v;
    __syncthreads();
    float s = red[0] + red[1] + red[2] + red[3];
    __syncthreads();
    return s;
}

// window row r -> flat pixel index under fold + roll(+3)
__device__ __forceinline__ int fold_pix(int r) {
    int bw = r / TT, t = r - bw * TT;
    int b = bw >> 6, nw = bw & 63;
    int wy = nw >> 3, wx = nw & 7;
    int ty = t / WS, tx = t - ty * WS;
    int hh = wy * WS + ty + SS; if (hh >= HH) hh -= HH;
    int ww = wx * WS + tx + SS; if (ww >= WW2) ww -= WW2;
    return b * HWP + hh * WW2 + ww;
}

// ---------------- transpose: [B][HW][C] -> [B][C][HW] ----------------
__global__ __launch_bounds__(256) void k_transpose_tm2cm(const float* __restrict__ in,
                                                         float* __restrict__ out) {
    __shared__ float tile[32][33];
    int b = blockIdx.z;
    int hw0 = blockIdx.x * 32;
    int c0 = blockIdx.y * 32;
    const float* src = in + (size_t)b * CC * HWP;
    float* dst = out + (size_t)b * CC * HWP;
    for (int i = threadIdx.y; i < 32; i += 8)
        tile[i][threadIdx.x] = src[(size_t)(hw0 + i) * CC + c0 + threadIdx.x];
    __syncthreads();
    for (int i = threadIdx.y; i < 32; i += 8)
        dst[(size_t)(c0 + i) * HWP + hw0 + threadIdx.x] = tile[threadIdx.x][i];
}

// ---------------- weight convert: [K][N] fp32 -> [N][K] bf16 (hi only) ----------------
__global__ __launch_bounds__(256) void k_wtcvt(const float* __restrict__ W, int K, int N,
                                               short* __restrict__ out) {
    __shared__ float tile[32][33];
    int n0 = blockIdx.x * 32, k0 = blockIdx.y * 32;
    int tx = threadIdx.x & 31, ty = threadIdx.x >> 5;
    for (int i = ty; i < 32; i += 8)
        tile[i][tx] = W[(size_t)(k0 + i) * N + n0 + tx];
    __syncthreads();
    for (int i = ty; i < 32; i += 8)
        out[(size_t)(n0 + i) * K + k0 + tx] = f2bf(tile[tx][i]);
}

// ---------------- activation pack: [M][Kf] fp32 -> [M][2Kf] bf16 [hi|lo] ----------------
__global__ __launch_bounds__(256) void k_apack(const float* __restrict__ in,
                                               short* __restrict__ out, int Kf) {
    int m = blockIdx.x;
    for (int c = threadIdx.x; c < Kf; c += 256) {
        float v = in[(size_t)m * Kf + c];
        short h = f2bf(v);
        out[(size_t)m * 2 * Kf + c] = h;
        out[(size_t)m * 2 * Kf + Kf + c] = f2bf(v - bf2f(h));
    }
}

// ---------------- MFMA GEMM, packed-A [Ah|Al], bf16 weight plane B[N][ldk] ----------------
// C = act((Ah+Al) @ B^T + bias). 128x128 tile, BK=64, 4 waves, global_load_lds,
// XOR-swizzled LDS (pre-swizzled source + swizzled ds_read; rule both-sides).
// PACK=1: output written as [hi(ldo)|lo(ldo)] shorts with row stride 2*ldo.
template<int ACT, int BETA, int PACK>
__global__ __launch_bounds__(256) void k_mgemm2(
    const short* __restrict__ A, int lda2, int K,
    const short* __restrict__ B, int ldk,
    const float* __restrict__ bias,
    float* __restrict__ Of, short* __restrict__ Os, int ldo)
{
    __shared__ short sAh[128 * 64];
    __shared__ short sAl[128 * 64];
    __shared__ short sB [128 * 64];
    int tid = threadIdx.x;
    int w = tid >> 6, lane = tid & 63;
    int wm = w >> 1, wn = w & 1;
    int lrow = lane & 15, kgrp = lane >> 4;
    int m0 = blockIdx.y * 128, n0 = blockIdx.x * 128;

    int srow8 = lane >> 3;                 // 0..7 (row within 8-row region)
    int clog  = (lane & 7) ^ srow8;        // swizzled logical k-group for this lane

    f32x4 acc[4][4] = {};

    for (int k0 = 0; k0 < K; k0 += 64) {
        #pragma unroll
        for (int i = 0; i < 4; ++i) {
            int r = w * 4 + i;                 // wave-uniform region 0..15
            int row = r * 8 + srow8;
            const short* ga = A + (size_t)(m0 + row) * lda2 + k0 + clog * 8;
            const short* gb = B + (size_t)(n0 + row) * ldk  + k0 + clog * 8;
            gl_lds16(ga,     &sAh[r * 512]);
            gl_lds16(ga + K, &sAl[r * 512]);
            gl_lds16(gb,     &sB [r * 512]);
        }
        asm volatile("s_waitcnt vmcnt(0)" ::: "memory");
        __syncthreads();

        bf16x8 ah[4][2], al[4][2];
        #pragma unroll
        for (int mi = 0; mi < 4; ++mi) {
            int rr = wm * 64 + mi * 16 + lrow;
            int base = rr * 64, swz = rr & 7;
            #pragma unroll
            for (int ks = 0; ks < 2; ++ks) {
                int off = base + (((ks * 4 + kgrp) ^ swz) << 3);
                ah[mi][ks] = *(const bf16x8*)&sAh[off];
                al[mi][ks] = *(const bf16x8*)&sAl[off];
            }
        }
        #pragma unroll
        for (int ni = 0; ni < 4; ++ni) {
            int rr = wn * 64 + ni * 16 + lrow;
            int base = rr * 64, swz = rr & 7;
            bf16x8 bb0 = *(const bf16x8*)&sB[base + (((kgrp    ) ^ swz) << 3)];
            bf16x8 bb1 = *(const bf16x8*)&sB[base + (((kgrp + 4) ^ swz) << 3)];
            #pragma unroll
            for (int mi = 0; mi < 4; ++mi) {
                acc[mi][ni] = __builtin_amdgcn_mfma_f32_16x16x32_bf16(ah[mi][0], bb0, acc[mi][ni], 0, 0, 0);
                acc[mi][ni] = __builtin_amdgcn_mfma_f32_16x16x32_bf16(al[mi][0], bb0, acc[mi][ni], 0, 0, 0);
                acc[mi][ni] = __builtin_amdgcn_mfma_f32_16x16x32_bf16(ah[mi][1], bb1, acc[mi][ni], 0, 0, 0);
                acc[mi][ni] = __builtin_amdgcn_mfma_f32_16x16x32_bf16(al[mi][1], bb1, acc[mi][ni], 0, 0, 0);
            }
        }
        __syncthreads();
    }

    #pragma unroll
    for (int mi = 0; mi < 4; ++mi)
        #pragma unroll
        for (int ni = 0; ni < 4; ++ni) {
            int col = n0 + wn * 64 + ni * 16 + lrow;
            int rb  = m0 + wm * 64 + mi * 16 + kgrp * 4;
            float bv = (BETA == 0) ? bias[col] : 0.0f;
            #pragma unroll
            for (int r = 0; r < 4; ++r) {
                float v = acc[mi][ni][r];
                if (BETA) {
                    Of[(size_t)(rb + r) * ldo + col] += v;
                } else {
                    v += bv;
                    if (ACT) v = gelu_exact(v);
                    if (PACK) {
                        short h = f2bf(v);
                        size_t ob = (size_t)(rb + r) * (2 * ldo) + col;
                        Os[ob] = h;
                        Os[ob + ldo] = f2bf(v - bf2f(h));
                    } else {
                        Of[(size_t)(rb + r) * ldo + col] = v;
                    }
                }
            }
        }
}

// ---------------- window gather from channel-major visual -> packed bf16 ----------------
__global__ __launch_bounds__(256) void k_gather_cm(const float* __restrict__ vis,
                                                   short* __restrict__ dst) {
    int r = blockIdx.x;
    int p = fold_pix(r);
    int b = p / HWP, hw = p - b * HWP;
    const float* src = vis + (size_t)b * CC * HWP + hw;
    short* d = dst + (size_t)r * 1024;
    int c = threadIdx.x;
    float v0 = src[(size_t)c * HWP];
    float v1 = src[(size_t)(c + 256) * HWP];
    short h0 = f2bf(v0); d[c]       = h0; d[512 + c] = f2bf(v0 - bf2f(h0));
    short h1 = f2bf(v1); d[c + 256] = h1; d[768 + c] = f2bf(v1 - bf2f(h1));
}

// ---------------- window gather of packed rows (skip -> pq) ----------------
__global__ __launch_bounds__(128) void k_gather_win(const short* __restrict__ srcP,
                                                    short* __restrict__ dst) {
    int r = blockIdx.x;
    int p = fold_pix(r);
    const uint4* s4 = (const uint4*)(srcP + (size_t)p * 1024);
    uint4* d4 = (uint4*)(dst + (size_t)r * 1024);
    d4[threadIdx.x] = s4[threadIdx.x];
}

// ---------------- meta MLP relative-position bias: biasT[h][i*49+j] ----------------
__global__ __launch_bounds__(256) void k_meta(const float* __restrict__ w1,
                                              const float* __restrict__ b1,
                                              const float* __restrict__ w2,
                                              const float* __restrict__ b2,
                                              float* __restrict__ biasT) {
    int id = blockIdx.x * 256 + threadIdx.x;
    if (id >= NH * TT * TT) return;
    int h = id / (TT * TT), p = id - h * (TT * TT);
    int i = p / TT, j = p - i * TT;
    float fy = (float)(i / WS - j / WS);
    float fx = (float)(i % WS - j % WS);
    float r0 = (fy > 0.f ? 1.f : (fy < 0.f ? -1.f : 0.f)) * log1pf(fabsf(fy));
    float r1 = (fx > 0.f ? 1.f : (fx < 0.f ? -1.f : 0.f)) * log1pf(fabsf(fx));
    float acc = 0.f;
    for (int m = 0; m < 256; ++m) {
        float hv = fmaxf(r0 * w1[m] + r1 * w1[256 + m] + b1[m], 0.f);
        acc += hv * w2[m * NH + h];
    }
    biasT[id] = acc + b2[h];
}

// ---------------- window attention -> packed bf16 wout ----------------
__global__ __launch_bounds__(256) void k_winattn(const float* __restrict__ qkv,
                                                 const float* __restrict__ biasT,
                                                 const float* __restrict__ tau,
                                                 short* __restrict__ woutP) {
    __shared__ float qs_t[HD * 65];     // [32][65] transposed, padded
    __shared__ float ks_t[HD * 65];
    __shared__ float vs[TT * HD];       // [49][32]
    __shared__ float sc[TT * 64];
    __shared__ float qn_sh[TT];
    int bw = blockIdx.x, h = blockIdx.y;
    int nw = bw & 63;
    int wy = nw >> 3, wx = nw & 7;
    int tid = threadIdx.x;
    int w = tid >> 6, j = tid & 63;

    for (int idx = tid; idx < TT * HD; idx += 256) {
        int t = idx >> 5, d = idx & 31;
        size_t g = (size_t)(bw * TT + t) * 1536 + h * HD + d;
        qs_t[d * 65 + t] = qkv[g];
        ks_t[d * 65 + t] = qkv[g + 512];
        vs[idx] = qkv[g + 1024];
    }
    for (int idx = tid; idx < HD * 16; idx += 256) {
        int d = idx >> 4, t = TT + (idx & 15);
        qs_t[d * 65 + t] = 0.f;
        ks_t[d * 65 + t] = 0.f;
    }
    __syncthreads();

    float kk = 0.f, qq = 0.f;
    #pragma unroll
    for (int d = 0; d < HD; ++d) {
        float k = ks_t[d * 65 + j]; kk += k * k;
        float q = qs_t[d * 65 + j]; qq += q * q;
    }
    float kn = sqrtf(kk);
    if (tid < TT) qn_sh[tid] = sqrtf(qq);
    __syncthreads();

    float inv_ts = 1.0f / fmaxf(tau[h], 0.01f);
    int hj = wy * WS + (j < TT ? j / WS : 0), wj = wx * WS + (j < TT ? j % WS : 0);
    int rj = (hj < 49 ? 0 : (hj < 53 ? 1 : 2)) * 3 + (wj < 49 ? 0 : (wj < 53 ? 1 : 2));

    for (int i = w; i < TT; i += 4) {
        float dot = 0.f;
        #pragma unroll
        for (int d = 0; d < HD; ++d)
            dot += qs_t[d * 65 + i] * ks_t[d * 65 + j];   // q broadcast, k conflict-free
        float a;
        if (j < TT) {
            float den = fmaxf(qn_sh[i] * kn, 1e-6f);
            a = dot / den * inv_ts + biasT[h * (TT * TT) + i * TT + j];
            int hi = wy * WS + i / WS, wi = wx * WS + i % WS;
            int ri = (hi < 49 ? 0 : (hi < 53 ? 1 : 2)) * 3 + (wi < 49 ? 0 : (wi < 53 ? 1 : 2));
            if (ri != rj) a -= 100.0f;
        } else {
            a = -1e30f;
        }
        float m = a;
        #pragma unroll
        for (int o = 32; o > 0; o >>= 1) m = fmaxf(m, __shfl_xor(m, o, 64));
        float e = expf(a - m);
        float s = e;
        #pragma unroll
        for (int o = 32; o > 0; o >>= 1) s += __shfl_xor(s, o, 64);
        sc[i * 64 + j] = e / s;
    }
    __syncthreads();

    for (int idx = tid; idx < TT * HD; idx += 256) {
        int i = idx >> 5, d = idx & 31;
        float acc = 0.f;
        for (int jj = 0; jj < TT; ++jj) acc += sc[i * 64 + jj] * vs[jj * HD + d];
        short hi = f2bf(acc);
        size_t ob = (size_t)(bw * TT + i) * 1024 + h * HD + d;
        woutP[ob] = hi;
        woutP[ob + 512] = f2bf(acc - bf2f(hi));
    }
}

// ---------------- cross attention -> packed bf16 co ----------------
__global__ __launch_bounds__(256) void k_crossattn(const float* __restrict__ q2,
                                                   const float* __restrict__ kv2,
                                                   short* __restrict__ coP) {
    __shared__ float qs_t[HD * 65];
    __shared__ float ks_t[HD * 65];
    __shared__ float vs[LL * HD];
    __shared__ float sc[TT * 64];
    int bw = blockIdx.x, h = blockIdx.y;
    int bvec = bw & 7;
    int tid = threadIdx.x;
    int w = tid >> 6, j = tid & 63;

    for (int idx = tid; idx < TT * HD; idx += 256) {
        int t = idx >> 5, d = idx & 31;
        qs_t[d * 65 + t] = q2[(size_t)(bw * TT + t) * CC + h * HD + d];
    }
    for (int idx = tid; idx < LL * HD; idx += 256) {
        int l = idx >> 5, d = idx & 31;
        size_t g = (size_t)(bvec * LL + l) * 1024 + h * HD + d;
        ks_t[d * 65 + l] = kv2[g];
        vs[idx] = kv2[g + 512];
    }
    __syncthreads();

    const float scale = 0.17677669529663687f;  // 32^-0.5
    for (int i = w; i < TT; i += 4) {
        float dot = 0.f;
        #pragma unroll
        for (int d = 0; d < HD; ++d)
            dot += qs_t[d * 65 + i] * ks_t[d * 65 + j];
        float a = dot * scale;
        float m = a;
        #pragma unroll
        for (int o = 32; o > 0; o >>= 1) m = fmaxf(m, __shfl_xor(m, o, 64));
        float e = expf(a - m);
        float s = e;
        #pragma unroll
        for (int o = 32; o > 0; o >>= 1) s += __shfl_xor(s, o, 64);
        sc[i * 64 + j] = e / s;
    }
    __syncthreads();

    for (int idx = tid; idx < TT * HD; idx += 256) {
        int i = idx >> 5, d = idx & 31;
        float acc = 0.f;
        for (int l = 0; l < LL; ++l) acc += sc[i * 64 + l] * vs[l * HD + d];
        short hi = f2bf(acc);
        size_t ob = (size_t)(bw * TT + i) * 1024 + h * HD + d;
        coP[ob] = hi;
        coP[ob + 512] = f2bf(acc - bf2f(hi));
    }
}

// ---------------- skip = LN1(fold(proj)) + visual  -> packed skip ----------------
__global__ __launch_bounds__(256) void k_ln1_fold(const float* __restrict__ proj,
                                                  const float* __restrict__ vis,
                                                  const float* __restrict__ g,
                                                  const float* __restrict__ bta,
                                                  short* __restrict__ skipP) {
    __shared__ float red[4];
    int r = blockIdx.x;
    int p = fold_pix(r);
    int b = p / HWP, hw = p - b * HWP;
    const float* row = proj + (size_t)r * CC;
    int c0 = threadIdx.x, c1 = threadIdx.x + 256;
    float x0 = row[c0], x1 = row[c1];
    float mu = blk_sum256(x0 + x1, red) * (1.f / CC);
    float d0 = x0 - mu, d1 = x1 - mu;
    float var = blk_sum256(d0 * d0 + d1 * d1, red) * (1.f / CC);
    float rstd = rsqrtf(var + 1e-5f);
    const float* vb = vis + (size_t)b * CC * HWP + hw;
    float y0 = d0 * rstd * g[c0] + bta[c0] + vb[(size_t)c0 * HWP];
    float y1 = d1 * rstd * g[c1] + bta[c1] + vb[(size_t)c1 * HWP];
    size_t o = (size_t)p * 1024;
    short h0 = f2bf(y0); skipP[o + c0] = h0; skipP[o + 512 + c0] = f2bf(y0 - bf2f(h0));
    short h1 = f2bf(y1); skipP[o + c1] = h1; skipP[o + 512 + c1] = f2bf(y1 - bf2f(h1));
}

// ---------------- skip += LN2(fold(cout))  (packed RMW) ----------------
__global__ __launch_bounds__(256) void k_ln2_fold_add(const float* __restrict__ cout_,
                                                      const float* __restrict__ g,
                                                      const float* __restrict__ bta,
                                                      short* __restrict__ skipP) {
    __shared__ float red[4];
    int r = blockIdx.x;
    int p = fold_pix(r);
    const float* row = cout_ + (size_t)r * CC;
    int c0 = threadIdx.x, c1 = threadIdx.x + 256;
    float x0 = row[c0], x1 = row[c1];
    float mu = blk_sum256(x0 + x1, red) * (1.f / CC);
    float d0 = x0 - mu, d1 = x1 - mu;
    float var = blk_sum256(d0 * d0 + d1 * d1, red) * (1.f / CC);
    float rstd = rsqrtf(var + 1e-5f);
    size_t o = (size_t)p * 1024;
    float s0 = bf2f(skipP[o + c0]) + bf2f(skipP[o + 512 + c0]);
    float s1 = bf2f(skipP[o + c1]) + bf2f(skipP[o + 512 + c1]);
    float y0 = s0 + d0 * rstd * g[c0] + bta[c0];
    float y1 = s1 + d1 * rstd * g[c1] + bta[c1];
    short h0 = f2bf(y0); skipP[o + c0] = h0; skipP[o + 512 + c0] = f2bf(y0 - bf2f(h0));
    short h1 = f2bf(y1); skipP[o + c1] = h1; skipP[o + 512 + c1] = f2bf(y1 - bf2f(h1));
}

// ---------------- final = skip + LN3(ff2) ----------------
__global__ __launch_bounds__(256) void k_ln3_final(const float* __restrict__ ff2,
                                                   const short* __restrict__ skipP,
                                                   const float* __restrict__ g,
                                                   const float* __restrict__ bta,
                                                   float* __restrict__ fin) {
    __shared__ float red[4];
    size_t p = blockIdx.x;
    const float* row = ff2 + p * CC;
    int c0 = threadIdx.x, c1 = threadIdx.x + 256;
    float x0 = row[c0], x1 = row[c1];
    float mu = blk_sum256(x0 + x1, red) * (1.f / CC);
    float d0 = x0 - mu, d1 = x1 - mu;
    float var = blk_sum256(d0 * d0 + d1 * d1, red) * (1.f / CC);
    float rstd = rsqrtf(var + 1e-5f);
    size_t o = p * 1024;
    float s0 = bf2f(skipP[o + c0]) + bf2f(skipP[o + 512 + c0]);
    float s1 = bf2f(skipP[o + c1]) + bf2f(skipP[o + 512 + c1]);
    fin[p * CC + c0] = s0 + d0 * rstd * g[c0] + bta[c0];
    fin[p * CC + c1] = s1 + d1 * rstd * g[c1] + bta[c1];
}

// ---------------- host launch ----------------
extern "C" void kernel_launch(void* const* d_in, const int* in_sizes, int n_in,
                              void* d_out, int out_size, void* d_ws, size_t ws_size,
                              hipStream_t stream) {
    const float* visual  = (const float*)d_in[0];
    const float* vector  = (const float*)d_in[1];
    const float* tm_w    = (const float*)d_in[2];
    const float* tm_b    = (const float*)d_in[3];
    const float* ln1_g   = (const float*)d_in[4];
    const float* ln1_b   = (const float*)d_in[5];
    const float* ln2_g   = (const float*)d_in[6];
    const float* ln2_b   = (const float*)d_in[7];
    const float* ln3_g   = (const float*)d_in[8];
    const float* ln3_b   = (const float*)d_in[9];
    const float* qkv_w   = (const float*)d_in[10];
    const float* qkv_b   = (const float*)d_in[11];
    const float* wproj_w = (const float*)d_in[12];
    const float* wproj_b = (const float*)d_in[13];
    const float* meta_w1 = (const float*)d_in[14];
    const float* meta_b1 = (const float*)d_in[15];
    const float* meta_w2 = (const float*)d_in[16];
    const float* meta_b2 = (const float*)d_in[17];
    const float* tau     = (const float*)d_in[18];
    const float* ca_in_w = (const float*)d_in[19];
    const float* ca_in_b = (const float*)d_in[20];
    const float* ca_out_w= (const float*)d_in[21];
    const float* ca_out_b= (const float*)d_in[22];
    const float* ff_w1   = (const float*)d_in[23];
    const float* ff_b1   = (const float*)d_in[24];
    const float* ff_w2   = (const float*)d_in[25];
    const float* ff_b2   = (const float*)d_in[26];
    float* out = (float*)d_out;

    // workspace layout
    const size_t TOKC = (size_t)NTOK * CC;   // 12,845,056 floats
    float* ws    = (float*)d_ws;
    float* M0    = ws;                 // qkv[0:512] / proj / q2 / cout / ffhP / final
    float* M1    = ws + TOKC;          // qkv[512:1024] / coP / ffhP(cont.)
    float* M2    = ws + 2 * TOKC;      // qkv[1024:1536] / skipP (packed, persistent)
    float* kv2   = ws + 3 * TOKC;                 // [512][1024] fp32
    float* biasT = kv2 + 524288;                  // [NH][49*49]
    short* SP    = (short*)(biasT + 38416);
    size_t so = 0;
    short* vecP  = SP + so; so += 524288;   // [512][1024] packed (tm output)
    short* vecAP = SP + so; so += 262144;   // [512][512]  packed (vector input)
    short* tmP   = SP + so; so += 131072;   // [512][256]
    short* qkvP  = SP + so; so += 786432;   // [1536][512]
    short* wprP  = SP + so; so += 262144;   // [512][512]
    short* caiP  = SP + so; so += 786432;   // [1536][512]
    short* caoP  = SP + so; so += 262144;   // [512][512]
    short* ff1P  = SP + so; so += 1048576;  // [2048][512]
    short* ff2P  = SP + so; so += 1048576;  // [512][2048]

    float* dscrF = out;                // d_out as scratch (fp32 ff2)
    short* dscrS = (short*)out;        // d_out as scratch (packed tok/wout/pq)
    short* skipP = (short*)M2;
    short* coP   = (short*)M1;
    short* ffhP  = (short*)M0;         // spans M0+M1: [NTOK][2048] shorts

    // 0. weight planes (bf16 hi, transposed [N][K])
    hipLaunchKernelGGL(k_wtcvt, dim3(16, 8),  dim3(256), 0, stream, tm_w,    256,  512,  tmP);
    hipLaunchKernelGGL(k_wtcvt, dim3(48, 16), dim3(256), 0, stream, qkv_w,   512,  1536, qkvP);
    hipLaunchKernelGGL(k_wtcvt, dim3(16, 16), dim3(256), 0, stream, wproj_w, 512,  512,  wprP);
    hipLaunchKernelGGL(k_wtcvt, dim3(48, 16), dim3(256), 0, stream, ca_in_w, 512,  1536, caiP);
    hipLaunchKernelGGL(k_wtcvt, dim3(16, 16), dim3(256), 0, stream, ca_out_w,512,  512,  caoP);
    hipLaunchKernelGGL(k_wtcvt, dim3(64, 16), dim3(256), 0, stream, ff_w1,   512,  2048, ff1P);
    hipLaunchKernelGGL(k_wtcvt, dim3(16, 64), dim3(256), 0, stream, ff_w2,   2048, 512,  ff2P);
    hipLaunchKernelGGL(k_apack, dim3(512), dim3(256), 0, stream, vector, vecAP, 256);

    // 1. vec = gelu(vector @ tm_w + tm_b) -> packed vecP
    hipLaunchKernelGGL((k_mgemm2<1,0,1>), dim3(4, 4), dim3(256), 0, stream,
                       vecAP, 512, 256, tmP, 256, tm_b, (float*)nullptr, vecP, 512);
    // 2. tokP = gather(visual) -> d_out
    hipLaunchKernelGGL(k_gather_cm, dim3(NTOK), dim3(256), 0, stream, visual, dscrS);
    // 3. qkv = tok @ qkv_w + b  -> M0..M2 fp32
    hipLaunchKernelGGL((k_mgemm2<0,0,0>), dim3(12, 196), dim3(256), 0, stream,
                       dscrS, 1024, 512, qkvP, 512, qkv_b, M0, (short*)nullptr, 1536);
    // 4. relative-position bias
    hipLaunchKernelGGL(k_meta, dim3((NH * TT * TT + 255) / 256), dim3(256), 0, stream,
                       meta_w1, meta_b1, meta_w2, meta_b2, biasT);
    // 5. window attention -> packed wout -> d_out
    hipLaunchKernelGGL(k_winattn, dim3(BW, NH), dim3(256), 0, stream,
                       M0, biasT, tau, dscrS);
    // 6. proj = wout @ wproj_w + b -> M0 fp32
    hipLaunchKernelGGL((k_mgemm2<0,0,0>), dim3(4, 196), dim3(256), 0, stream,
                       dscrS, 1024, 512, wprP, 512, wproj_b, M0, (short*)nullptr, 512);
    // 7. skipP = pack(LN1(fold(proj)) + visual) -> M2
    hipLaunchKernelGGL(k_ln1_fold, dim3(NTOK), dim3(256), 0, stream,
                       M0, visual, ln1_g, ln1_b, skipP);
    // 8. pqP = gather(skipP) -> d_out
    hipLaunchKernelGGL(k_gather_win, dim3(NTOK), dim3(128), 0, stream, skipP, dscrS);
    // 9. q2 = pq @ ca_in_w[:, :512] + bq -> M0 fp32
    hipLaunchKernelGGL((k_mgemm2<0,0,0>), dim3(4, 196), dim3(256), 0, stream,
                       dscrS, 1024, 512, caiP, 512, ca_in_b, M0, (short*)nullptr, 512);
    // 10. kv2 = vec @ ca_in_w[:, 512:] + b[512:] -> fp32
    hipLaunchKernelGGL((k_mgemm2<0,0,0>), dim3(8, 4), dim3(256), 0, stream,
                       vecP, 1024, 512, caiP + (size_t)512 * 512, 512, ca_in_b + 512,
                       kv2, (short*)nullptr, 1024);
    // 11. cross attention -> packed co -> M1
    hipLaunchKernelGGL(k_crossattn, dim3(BW, NH), dim3(256), 0, stream,
                       M0, kv2, coP);
    // 12. cout = co @ ca_out_w + b -> M0 fp32
    hipLaunchKernelGGL((k_mgemm2<0,0,0>), dim3(4, 196), dim3(256), 0, stream,
                       coP, 1024, 512, caoP, 512, ca_out_b, M0, (short*)nullptr, 512);
    // 13. skipP += LN2(fold(cout))
    hipLaunchKernelGGL(k_ln2_fold_add, dim3(NTOK), dim3(256), 0, stream,
                       M0, ln2_g, ln2_b, skipP);
    // 14a. ffh_lo = gelu(skip @ ff_w1[:, :1024] + b1) -> packed -> M0M1
    hipLaunchKernelGGL((k_mgemm2<1,0,1>), dim3(8, 196), dim3(256), 0, stream,
                       skipP, 1024, 512, ff1P, 512, ff_b1, (float*)nullptr, (short*)ffhP, 1024);
    // 14b. ff2 = ffh_lo @ ff_w2[:1024, :] + b2 -> d_out fp32
    hipLaunchKernelGGL((k_mgemm2<0,0,0>), dim3(4, 196), dim3(256), 0, stream,
                       ffhP, 2048, 1024, ff2P, 2048, ff_b2, dscrF, (short*)nullptr, 512);
    // 14c. ffh_hi = gelu(skip @ ff_w1[:, 1024:] + b1[1024:]) -> packed -> M0M1
    hipLaunchKernelGGL((k_mgemm2<1,0,1>), dim3(8, 196), dim3(256), 0, stream,
                       skipP, 1024, 512, ff1P + (size_t)1024 * 512, 512, ff_b1 + 1024,
                       (float*)nullptr, (short*)ffhP, 1024);
    // 14d. ff2 += ffh_hi @ ff_w2[1024:, :]
    hipLaunchKernelGGL((k_mgemm2<0,1,0>), dim3(4, 196), dim3(256), 0, stream,
                       ffhP, 2048, 1024, ff2P + 1024, 2048, ff_b2, dscrF, (short*)nullptr, 512);
    // 15. final = skip + LN3(ff2) -> M0 fp32 (token-major)
    hipLaunchKernelGGL(k_ln3_final, dim3(NTOK), dim3(256), 0, stream,
                       dscrF, skipP, ln3_g, ln3_b, M0);
    // 16. final -> d_out (channel-major)
    hipLaunchKernelGGL(k_transpose_tm2cm, dim3(HWP / 32, CC / 32, BB), dim3(32, 8), 0, stream,
                       M0, out);
}

// Round 6
// 1165.359 us; speedup vs baseline: 3.2624x; 1.1786x over previous
//
#include <hip/hip_runtime.h>
#include <hip/hip_bf16.h>
#include <cstdint>

// ---------------- problem constants ----------------
#define BB   8
#define CC   512
#define HH   56
#define WW2  56
#define HWP  3136          // 56*56
#define WS   7
#define SS   3
#define NH   16
#define HD   32
#define TT   49            // WS*WS
#define NW   64            // (56/7)^2
#define LL   64
#define BW   512           // BB*NW
#define NTOK 25088         // BW*TT == BB*HWP

typedef __attribute__((ext_vector_type(8))) short bf16x8;
typedef __attribute__((ext_vector_type(4))) float f32x4;

// ---------------- helpers ----------------
__device__ __forceinline__ float gelu_exact(float x) {
    return 0.5f * x * (1.0f + erff(x * 0.70710678118654752440f));
}
__device__ __forceinline__ short f2bf(float v) {
    __hip_bfloat16 b = __float2bfloat16(v);
    return *reinterpret_cast<short*>(&b);
}
__device__ __forceinline__ float bf2f(short s) {
    __hip_bfloat16 b = *reinterpret_cast<__hip_bfloat16*>(&s);
    return __bfloat162float(b);
}
__device__ __forceinline__ void gl_lds16(const void* g, void* l) {
    __builtin_amdgcn_global_load_lds(
        (const __attribute__((address_space(1))) void*)g,
        (__attribute__((address_space(3))) void*)l, 16, 0, 0);
}

__device__ __forceinline__ float blk_sum256(float v, volatile float* red) {
    #pragma unroll
    for (int o = 32; o > 0; o >>= 1) v += __shfl_down(v, o, 64);
    int lane = threadIdx.x & 63, w = threadIdx.x >> 6;
    if (lane == 0) red[w] = v;
    __syncthreads();
    float s = red[0] + red[1] + red[2] + red[3];
    __syncthreads();
    return s;
}

// window row r -> flat pixel index under fold + roll(+3)
__device__ __forceinline__ int fold_pix(int r) {
    int bw = r / TT, t = r - bw * TT;
    int b = bw >> 6, nw = bw & 63;
    int wy = nw >> 3, wx = nw & 7;
    int ty = t / WS, tx = t - ty * WS;
    int hh = wy * WS + ty + SS; if (hh >= HH) hh -= HH;
    int ww = wx * WS + tx + SS; if (ww >= WW2) ww -= WW2;
    return b * HWP + hh * WW2 + ww;
}

__device__ __forceinline__ int region_of(int hh, int ww) {
    return (hh < 49 ? 0 : (hh < 53 ? 1 : 2)) * 3 + (ww < 49 ? 0 : (ww < 53 ? 1 : 2));
}

// ---------------- transpose: [B][HW][C] -> [B][C][HW] ----------------
__global__ __launch_bounds__(256) void k_transpose_tm2cm(const float* __restrict__ in,
                                                         float* __restrict__ out) {
    __shared__ float tile[32][33];
    int b = blockIdx.z;
    int hw0 = blockIdx.x * 32;
    int c0 = blockIdx.y * 32;
    const float* src = in + (size_t)b * CC * HWP;
    float* dst = out + (size_t)b * CC * HWP;
    for (int i = threadIdx.y; i < 32; i += 8)
        tile[i][threadIdx.x] = src[(size_t)(hw0 + i) * CC + c0 + threadIdx.x];
    __syncthreads();
    for (int i = threadIdx.y; i < 32; i += 8)
        dst[(size_t)(c0 + i) * HWP + hw0 + threadIdx.x] = tile[threadIdx.x][i];
}

// ---------------- weight convert: [K][N] fp32 -> [N][K] bf16 (hi only) ----------------
__global__ __launch_bounds__(256) void k_wtcvt(const float* __restrict__ W, int K, int N,
                                               short* __restrict__ out) {
    __shared__ float tile[32][33];
    int n0 = blockIdx.x * 32, k0 = blockIdx.y * 32;
    int tx = threadIdx.x & 31, ty = threadIdx.x >> 5;
    for (int i = ty; i < 32; i += 8)
        tile[i][tx] = W[(size_t)(k0 + i) * N + n0 + tx];
    __syncthreads();
    for (int i = ty; i < 32; i += 8)
        out[(size_t)(n0 + i) * K + k0 + tx] = f2bf(tile[tx][i]);
}

// ---------------- activation pack: [M][Kf] fp32 -> [M][2Kf] bf16 [hi|lo] ----------------
__global__ __launch_bounds__(256) void k_apack(const float* __restrict__ in,
                                               short* __restrict__ out, int Kf) {
    int m = blockIdx.x;
    for (int c = threadIdx.x; c < Kf; c += 256) {
        float v = in[(size_t)m * Kf + c];
        short h = f2bf(v);
        out[(size_t)m * 2 * Kf + c] = h;
        out[(size_t)m * 2 * Kf + Kf + c] = f2bf(v - bf2f(h));
    }
}

// ---------------- MFMA GEMM, packed-A [Ah|Al], bf16 weight plane B[N][ldk] ----------------
template<int ACT, int BETA, int PACK>
__global__ __launch_bounds__(256) void k_mgemm2(
    const short* __restrict__ A, int lda2, int K,
    const short* __restrict__ B, int ldk,
    const float* __restrict__ bias,
    float* __restrict__ Of, short* __restrict__ Os, int ldo)
{
    __shared__ short sAh[128 * 64];
    __shared__ short sAl[128 * 64];
    __shared__ short sB [128 * 64];
    int tid = threadIdx.x;
    int w = tid >> 6, lane = tid & 63;
    int wm = w >> 1, wn = w & 1;
    int lrow = lane & 15, kgrp = lane >> 4;
    int m0 = blockIdx.y * 128, n0 = blockIdx.x * 128;

    int srow8 = lane >> 3;                 // 0..7 (row within 8-row region)
    int clog  = (lane & 7) ^ srow8;        // swizzled logical k-group for this lane

    f32x4 acc[4][4] = {};

    for (int k0 = 0; k0 < K; k0 += 64) {
        #pragma unroll
        for (int i = 0; i < 4; ++i) {
            int r = w * 4 + i;                 // wave-uniform region 0..15
            int row = r * 8 + srow8;
            const short* ga = A + (size_t)(m0 + row) * lda2 + k0 + clog * 8;
            const short* gb = B + (size_t)(n0 + row) * ldk  + k0 + clog * 8;
            gl_lds16(ga,     &sAh[r * 512]);
            gl_lds16(ga + K, &sAl[r * 512]);
            gl_lds16(gb,     &sB [r * 512]);
        }
        asm volatile("s_waitcnt vmcnt(0)" ::: "memory");
        __syncthreads();

        bf16x8 ah[4][2], al[4][2];
        #pragma unroll
        for (int mi = 0; mi < 4; ++mi) {
            int rr = wm * 64 + mi * 16 + lrow;
            int base = rr * 64, swz = rr & 7;
            #pragma unroll
            for (int ks = 0; ks < 2; ++ks) {
                int off = base + (((ks * 4 + kgrp) ^ swz) << 3);
                ah[mi][ks] = *(const bf16x8*)&sAh[off];
                al[mi][ks] = *(const bf16x8*)&sAl[off];
            }
        }
        #pragma unroll
        for (int ni = 0; ni < 4; ++ni) {
            int rr = wn * 64 + ni * 16 + lrow;
            int base = rr * 64, swz = rr & 7;
            bf16x8 bb0 = *(const bf16x8*)&sB[base + (((kgrp    ) ^ swz) << 3)];
            bf16x8 bb1 = *(const bf16x8*)&sB[base + (((kgrp + 4) ^ swz) << 3)];
            #pragma unroll
            for (int mi = 0; mi < 4; ++mi) {
                acc[mi][ni] = __builtin_amdgcn_mfma_f32_16x16x32_bf16(ah[mi][0], bb0, acc[mi][ni], 0, 0, 0);
                acc[mi][ni] = __builtin_amdgcn_mfma_f32_16x16x32_bf16(al[mi][0], bb0, acc[mi][ni], 0, 0, 0);
                acc[mi][ni] = __builtin_amdgcn_mfma_f32_16x16x32_bf16(ah[mi][1], bb1, acc[mi][ni], 0, 0, 0);
                acc[mi][ni] = __builtin_amdgcn_mfma_f32_16x16x32_bf16(al[mi][1], bb1, acc[mi][ni], 0, 0, 0);
            }
        }
        __syncthreads();
    }

    #pragma unroll
    for (int mi = 0; mi < 4; ++mi)
        #pragma unroll
        for (int ni = 0; ni < 4; ++ni) {
            int col = n0 + wn * 64 + ni * 16 + lrow;
            int rb  = m0 + wm * 64 + mi * 16 + kgrp * 4;
            float bv = (BETA == 0) ? bias[col] : 0.0f;
            #pragma unroll
            for (int r = 0; r < 4; ++r) {
                float v = acc[mi][ni][r];
                if (BETA) {
                    Of[(size_t)(rb + r) * ldo + col] += v;
                } else {
                    v += bv;
                    if (ACT) v = gelu_exact(v);
                    if (PACK) {
                        short h = f2bf(v);
                        size_t ob = (size_t)(rb + r) * (2 * ldo) + col;
                        Os[ob] = h;
                        Os[ob + ldo] = f2bf(v - bf2f(h));
                    } else {
                        Of[(size_t)(rb + r) * ldo + col] = v;
                    }
                }
            }
        }
}

// ---------------- window gather from channel-major visual -> packed bf16 ----------------
__global__ __launch_bounds__(256) void k_gather_cm(const float* __restrict__ vis,
                                                   short* __restrict__ dst) {
    int r = blockIdx.x;
    int p = fold_pix(r);
    int b = p / HWP, hw = p - b * HWP;
    const float* src = vis + (size_t)b * CC * HWP + hw;
    short* d = dst + (size_t)r * 1024;
    int c = threadIdx.x;
    float v0 = src[(size_t)c * HWP];
    float v1 = src[(size_t)(c + 256) * HWP];
    short h0 = f2bf(v0); d[c]       = h0; d[512 + c] = f2bf(v0 - bf2f(h0));
    short h1 = f2bf(v1); d[c + 256] = h1; d[768 + c] = f2bf(v1 - bf2f(h1));
}

// ---------------- window gather of packed rows (skip -> pq) ----------------
__global__ __launch_bounds__(128) void k_gather_win(const short* __restrict__ srcP,
                                                    short* __restrict__ dst) {
    int r = blockIdx.x;
    int p = fold_pix(r);
    const uint4* s4 = (const uint4*)(srcP + (size_t)p * 1024);
    uint4* d4 = (uint4*)(dst + (size_t)r * 1024);
    d4[threadIdx.x] = s4[threadIdx.x];
}

// ---------------- meta MLP bias -> padded bias2[h][64][64] ----------------
__global__ __launch_bounds__(256) void k_meta(const float* __restrict__ w1,
                                              const float* __restrict__ b1,
                                              const float* __restrict__ w2,
                                              const float* __restrict__ b2,
                                              float* __restrict__ bias2) {
    int id = blockIdx.x * 256 + threadIdx.x;   // NH*64*64
    int h = id >> 12, p = id & 4095;
    int i = p >> 6, j = p & 63;
    float val = 0.f;
    if (i < TT && j < TT) {
        float fy = (float)(i / WS - j / WS);
        float fx = (float)(i % WS - j % WS);
        float r0 = (fy > 0.f ? 1.f : (fy < 0.f ? -1.f : 0.f)) * log1pf(fabsf(fy));
        float r1 = (fx > 0.f ? 1.f : (fx < 0.f ? -1.f : 0.f)) * log1pf(fabsf(fx));
        float acc = 0.f;
        for (int m = 0; m < 256; ++m) {
            float hv = fmaxf(r0 * w1[m] + r1 * w1[256 + m] + b1[m], 0.f);
            acc += hv * w2[m * NH + h];
        }
        val = acc + b2[h];
    }
    bias2[id] = val;
}

// ---------------- MFMA window attention ----------------
// S^T formulation: per wave wv, output i-tile = wv*16..wv*16+15.
// QK^T: A=K frags (hi/lo), B=Q frags (hi/lo), 3-term. Softmax per lane-column.
// PV: A=Vt [d][j], B=P2 [i][j].
__global__ __launch_bounds__(256) void k_winattn(const float* __restrict__ qkv,
                                                 const float* __restrict__ bias2,
                                                 const float* __restrict__ tau,
                                                 short* __restrict__ woutP) {
    __shared__ short Qh[64 * 40], Ql[64 * 40], Kh[64 * 40], Kl[64 * 40];
    __shared__ short Vt[32 * 72];
    __shared__ short P2[64 * 72];
    __shared__ float qn[64], kn[64];
    int bw = blockIdx.x, h = blockIdx.y;
    int tid = threadIdx.x;
    int wv = tid >> 6, lane = tid & 63;

    // ---- stage: (t over passes, d = tid&31) ----
    int d = tid & 31, t0 = tid >> 5;
    for (int t = t0; t < 64; t += 8) {
        float q = 0.f, k = 0.f, v = 0.f;
        if (t < TT) {
            size_t g = (size_t)(bw * TT + t) * 1536 + h * HD + d;
            q = qkv[g]; k = qkv[g + 512]; v = qkv[g + 1024];
        }
        short qh = f2bf(q); Qh[t * 40 + d] = qh; Ql[t * 40 + d] = f2bf(q - bf2f(qh));
        short kh = f2bf(k); Kh[t * 40 + d] = kh; Kl[t * 40 + d] = f2bf(k - bf2f(kh));
        Vt[d * 72 + t] = f2bf(v);
        float qq = q * q, kk = k * k;
        #pragma unroll
        for (int o = 16; o > 0; o >>= 1) {
            qq += __shfl_xor(qq, o, 64);
            kk += __shfl_xor(kk, o, 64);
        }
        if (d == 0) { qn[t] = sqrtf(qq); kn[t] = sqrtf(kk); }
    }
    __syncthreads();

    int lrow = lane & 15, kg = lane >> 4;
    int i = wv * 16 + lrow;

    // ---- QK^T (S^T tiles) ----
    bf16x8 qbh = *(const bf16x8*)&Qh[i * 40 + kg * 8];
    bf16x8 qbl = *(const bf16x8*)&Ql[i * 40 + kg * 8];
    f32x4 st[4];
    #pragma unroll
    for (int jt = 0; jt < 4; ++jt) {
        bf16x8 kah = *(const bf16x8*)&Kh[(jt * 16 + lrow) * 40 + kg * 8];
        bf16x8 kal = *(const bf16x8*)&Kl[(jt * 16 + lrow) * 40 + kg * 8];
        f32x4 c = {0.f, 0.f, 0.f, 0.f};
        c = __builtin_amdgcn_mfma_f32_16x16x32_bf16(kah, qbh, c, 0, 0, 0);
        c = __builtin_amdgcn_mfma_f32_16x16x32_bf16(kal, qbh, c, 0, 0, 0);
        c = __builtin_amdgcn_mfma_f32_16x16x32_bf16(kah, qbl, c, 0, 0, 0);
        st[jt] = c;
    }

    // ---- softmax over j (per-lane 16 regs + 2 shfl) ----
    float inv_ts = 1.0f / fmaxf(tau[h], 0.01f);
    float qni = qn[i];
    int nw_ = bw & 63, wy = nw_ >> 3, wx = nw_ & 7;
    int ri = region_of(wy * WS + i / WS, wx * WS + i % WS);
    float av[4][4];
    float m = -1e30f;
    #pragma unroll
    for (int jt = 0; jt < 4; ++jt) {
        float4 bb = *(const float4*)&bias2[(size_t)h * 4096 + i * 64 + jt * 16 + kg * 4];
        const float* bbp = (const float*)&bb;
        #pragma unroll
        for (int r = 0; r < 4; ++r) {
            int j = jt * 16 + kg * 4 + r;
            float a = -1e30f;
            if (j < TT) {
                float den = fmaxf(qni * kn[j], 1e-6f);
                int rj = region_of(wy * WS + j / WS, wx * WS + j % WS);
                a = st[jt][r] / den * inv_ts + bbp[r];
                if (ri != rj) a -= 100.0f;
            }
            av[jt][r] = a;
            m = fmaxf(m, a);
        }
    }
    m = fmaxf(m, __shfl_xor(m, 16, 64));
    m = fmaxf(m, __shfl_xor(m, 32, 64));
    float s = 0.f;
    #pragma unroll
    for (int jt = 0; jt < 4; ++jt)
        #pragma unroll
        for (int r = 0; r < 4; ++r) {
            float e = expf(av[jt][r] - m);
            av[jt][r] = e; s += e;
        }
    s += __shfl_xor(s, 16, 64);
    s += __shfl_xor(s, 32, 64);
    float inv = 1.0f / s;
    #pragma unroll
    for (int jt = 0; jt < 4; ++jt) {
        short p4[4];
        #pragma unroll
        for (int r = 0; r < 4; ++r) p4[r] = f2bf(av[jt][r] * inv);
        *(uint2*)&P2[i * 72 + jt * 16 + kg * 4] = *(const uint2*)p4;
    }

    // ---- PV: O^T[d][i] (own-wave P2 rows only; no barrier needed) ----
    f32x4 o0 = {0.f, 0.f, 0.f, 0.f}, o1 = {0.f, 0.f, 0.f, 0.f};
    #pragma unroll
    for (int ks = 0; ks < 2; ++ks) {
        bf16x8 pb = *(const bf16x8*)&P2[i * 72 + ks * 32 + kg * 8];
        bf16x8 v0 = *(const bf16x8*)&Vt[lrow * 72 + ks * 32 + kg * 8];
        bf16x8 v1 = *(const bf16x8*)&Vt[(16 + lrow) * 72 + ks * 32 + kg * 8];
        o0 = __builtin_amdgcn_mfma_f32_16x16x32_bf16(v0, pb, o0, 0, 0, 0);
        o1 = __builtin_amdgcn_mfma_f32_16x16x32_bf16(v1, pb, o1, 0, 0, 0);
    }

    if (i < TT) {
        size_t ob = (size_t)(bw * TT + i) * 1024 + h * HD;
        #pragma unroll
        for (int r = 0; r < 4; ++r) {
            int d0 = kg * 4 + r;
            float va = o0[r], vb = o1[r];
            short ha = f2bf(va);
            woutP[ob + d0] = ha;
            woutP[ob + 512 + d0] = f2bf(va - bf2f(ha));
            short hb = f2bf(vb);
            woutP[ob + 16 + d0] = hb;
            woutP[ob + 512 + 16 + d0] = f2bf(vb - bf2f(hb));
        }
    }
}

// ---------------- MFMA cross attention (window bw attends to vec[bw % 8]) ----------------
__global__ __launch_bounds__(256) void k_crossattn(const float* __restrict__ q2,
                                                   const float* __restrict__ kv2,
                                                   short* __restrict__ coP) {
    __shared__ short Qh[64 * 40], Ql[64 * 40], Kh[64 * 40], Kl[64 * 40];
    __shared__ short Vt[32 * 72];
    __shared__ short P2[64 * 72];
    int bw = blockIdx.x, h = blockIdx.y;
    int bvec = bw & 7;
    int tid = threadIdx.x;
    int wv = tid >> 6, lane = tid & 63;

    int d = tid & 31, t0 = tid >> 5;
    for (int t = t0; t < 64; t += 8) {
        float q = 0.f;
        if (t < TT)
            q = q2[(size_t)(bw * TT + t) * CC + h * HD + d];
        size_t g = (size_t)(bvec * LL + t) * 1024 + h * HD + d;
        float k = kv2[g];
        float v = kv2[g + 512];
        short qh = f2bf(q); Qh[t * 40 + d] = qh; Ql[t * 40 + d] = f2bf(q - bf2f(qh));
        short kh = f2bf(k); Kh[t * 40 + d] = kh; Kl[t * 40 + d] = f2bf(k - bf2f(kh));
        Vt[d * 72 + t] = f2bf(v);
    }
    __syncthreads();

    int lrow = lane & 15, kg = lane >> 4;
    int i = wv * 16 + lrow;

    bf16x8 qbh = *(const bf16x8*)&Qh[i * 40 + kg * 8];
    bf16x8 qbl = *(const bf16x8*)&Ql[i * 40 + kg * 8];
    f32x4 st[4];
    #pragma unroll
    for (int jt = 0; jt < 4; ++jt) {
        bf16x8 kah = *(const bf16x8*)&Kh[(jt * 16 + lrow) * 40 + kg * 8];
        bf16x8 kal = *(const bf16x8*)&Kl[(jt * 16 + lrow) * 40 + kg * 8];
        f32x4 c = {0.f, 0.f, 0.f, 0.f};
        c = __builtin_amdgcn_mfma_f32_16x16x32_bf16(kah, qbh, c, 0, 0, 0);
        c = __builtin_amdgcn_mfma_f32_16x16x32_bf16(kal, qbh, c, 0, 0, 0);
        c = __builtin_amdgcn_mfma_f32_16x16x32_bf16(kah, qbl, c, 0, 0, 0);
        st[jt] = c;
    }

    const float scale = 0.17677669529663687f;  // 32^-0.5
    float av[4][4];
    float m = -1e30f;
    #pragma unroll
    for (int jt = 0; jt < 4; ++jt)
        #pragma unroll
        for (int r = 0; r < 4; ++r) {
            float a = st[jt][r] * scale;
            av[jt][r] = a;
            m = fmaxf(m, a);
        }
    m = fmaxf(m, __shfl_xor(m, 16, 64));
    m = fmaxf(m, __shfl_xor(m, 32, 64));
    float s = 0.f;
    #pragma unroll
    for (int jt = 0; jt < 4; ++jt)
        #pragma unroll
        for (int r = 0; r < 4; ++r) {
            float e = expf(av[jt][r] - m);
            av[jt][r] = e; s += e;
        }
    s += __shfl_xor(s, 16, 64);
    s += __shfl_xor(s, 32, 64);
    float inv = 1.0f / s;
    #pragma unroll
    for (int jt = 0; jt < 4; ++jt) {
        short p4[4];
        #pragma unroll
        for (int r = 0; r < 4; ++r) p4[r] = f2bf(av[jt][r] * inv);
        *(uint2*)&P2[i * 72 + jt * 16 + kg * 4] = *(const uint2*)p4;
    }

    f32x4 o0 = {0.f, 0.f, 0.f, 0.f}, o1 = {0.f, 0.f, 0.f, 0.f};
    #pragma unroll
    for (int ks = 0; ks < 2; ++ks) {
        bf16x8 pb = *(const bf16x8*)&P2[i * 72 + ks * 32 + kg * 8];
        bf16x8 v0 = *(const bf16x8*)&Vt[lrow * 72 + ks * 32 + kg * 8];
        bf16x8 v1 = *(const bf16x8*)&Vt[(16 + lrow) * 72 + ks * 32 + kg * 8];
        o0 = __builtin_amdgcn_mfma_f32_16x16x32_bf16(v0, pb, o0, 0, 0, 0);
        o1 = __builtin_amdgcn_mfma_f32_16x16x32_bf16(v1, pb, o1, 0, 0, 0);
    }

    if (i < TT) {
        size_t ob = (size_t)(bw * TT + i) * 1024 + h * HD;
        #pragma unroll
        for (int r = 0; r < 4; ++r) {
            int d0 = kg * 4 + r;
            float va = o0[r], vb = o1[r];
            short ha = f2bf(va);
            coP[ob + d0] = ha;
            coP[ob + 512 + d0] = f2bf(va - bf2f(ha));
            short hb = f2bf(vb);
            coP[ob + 16 + d0] = hb;
            coP[ob + 512 + 16 + d0] = f2bf(vb - bf2f(hb));
        }
    }
}

// ---------------- skip = LN1(fold(proj)) + visual  -> packed skip ----------------
__global__ __launch_bounds__(256) void k_ln1_fold(const float* __restrict__ proj,
                                                  const float* __restrict__ vis,
                                                  const float* __restrict__ g,
                                                  const float* __restrict__ bta,
                                                  short* __restrict__ skipP) {
    __shared__ float red[4];
    int r = blockIdx.x;
    int p = fold_pix(r);
    int b = p / HWP, hw = p - b * HWP;
    const float* row = proj + (size_t)r * CC;
    int c0 = threadIdx.x, c1 = threadIdx.x + 256;
    float x0 = row[c0], x1 = row[c1];
    float mu = blk_sum256(x0 + x1, red) * (1.f / CC);
    float d0 = x0 - mu, d1 = x1 - mu;
    float var = blk_sum256(d0 * d0 + d1 * d1, red) * (1.f / CC);
    float rstd = rsqrtf(var + 1e-5f);
    const float* vb = vis + (size_t)b * CC * HWP + hw;
    float y0 = d0 * rstd * g[c0] + bta[c0] + vb[(size_t)c0 * HWP];
    float y1 = d1 * rstd * g[c1] + bta[c1] + vb[(size_t)c1 * HWP];
    size_t o = (size_t)p * 1024;
    short h0 = f2bf(y0); skipP[o + c0] = h0; skipP[o + 512 + c0] = f2bf(y0 - bf2f(h0));
    short h1 = f2bf(y1); skipP[o + c1] = h1; skipP[o + 512 + c1] = f2bf(y1 - bf2f(h1));
}

// ---------------- skip += LN2(fold(cout))  (packed RMW) ----------------
__global__ __launch_bounds__(256) void k_ln2_fold_add(const float* __restrict__ cout_,
                                                      const float* __restrict__ g,
                                                      const float* __restrict__ bta,
                                                      short* __restrict__ skipP) {
    __shared__ float red[4];
    int r = blockIdx.x;
    int p = fold_pix(r);
    const float* row = cout_ + (size_t)r * CC;
    int c0 = threadIdx.x, c1 = threadIdx.x + 256;
    float x0 = row[c0], x1 = row[c1];
    float mu = blk_sum256(x0 + x1, red) * (1.f / CC);
    float d0 = x0 - mu, d1 = x1 - mu;
    float var = blk_sum256(d0 * d0 + d1 * d1, red) * (1.f / CC);
    float rstd = rsqrtf(var + 1e-5f);
    size_t o = (size_t)p * 1024;
    float s0 = bf2f(skipP[o + c0]) + bf2f(skipP[o + 512 + c0]);
    float s1 = bf2f(skipP[o + c1]) + bf2f(skipP[o + 512 + c1]);
    float y0 = s0 + d0 * rstd * g[c0] + bta[c0];
    float y1 = s1 + d1 * rstd * g[c1] + bta[c1];
    short h0 = f2bf(y0); skipP[o + c0] = h0; skipP[o + 512 + c0] = f2bf(y0 - bf2f(h0));
    short h1 = f2bf(y1); skipP[o + c1] = h1; skipP[o + 512 + c1] = f2bf(y1 - bf2f(h1));
}

// ---------------- final = skip + LN3(ff2) ----------------
__global__ __launch_bounds__(256) void k_ln3_final(const float* __restrict__ ff2,
                                                   const short* __restrict__ skipP,
                                                   const float* __restrict__ g,
                                                   const float* __restrict__ bta,
                                                   float* __restrict__ fin) {
    __shared__ float red[4];
    size_t p = blockIdx.x;
    const float* row = ff2 + p * CC;
    int c0 = threadIdx.x, c1 = threadIdx.x + 256;
    float x0 = row[c0], x1 = row[c1];
    float mu = blk_sum256(x0 + x1, red) * (1.f / CC);
    float d0 = x0 - mu, d1 = x1 - mu;
    float var = blk_sum256(d0 * d0 + d1 * d1, red) * (1.f / CC);
    float rstd = rsqrtf(var + 1e-5f);
    size_t o = p * 1024;
    float s0 = bf2f(skipP[o + c0]) + bf2f(skipP[o + 512 + c0]);
    float s1 = bf2f(skipP[o + c1]) + bf2f(skipP[o + 512 + c1]);
    fin[p * CC + c0] = s0 + d0 * rstd * g[c0] + bta[c0];
    fin[p * CC + c1] = s1 + d1 * rstd * g[c1] + bta[c1];
}

// ---------------- host launch ----------------
extern "C" void kernel_launch(void* const* d_in, const int* in_sizes, int n_in,
                              void* d_out, int out_size, void* d_ws, size_t ws_size,
                              hipStream_t stream) {
    const float* visual  = (const float*)d_in[0];
    const float* vector  = (const float*)d_in[1];
    const float* tm_w    = (const float*)d_in[2];
    const float* tm_b    = (const float*)d_in[3];
    const float* ln1_g   = (const float*)d_in[4];
    const float* ln1_b   = (const float*)d_in[5];
    const float* ln2_g   = (const float*)d_in[6];
    const float* ln2_b   = (const float*)d_in[7];
    const float* ln3_g   = (const float*)d_in[8];
    const float* ln3_b   = (const float*)d_in[9];
    const float* qkv_w   = (const float*)d_in[10];
    const float* qkv_b   = (const float*)d_in[11];
    const float* wproj_w = (const float*)d_in[12];
    const float* wproj_b = (const float*)d_in[13];
    const float* meta_w1 = (const float*)d_in[14];
    const float* meta_b1 = (const float*)d_in[15];
    const float* meta_w2 = (const float*)d_in[16];
    const float* meta_b2 = (const float*)d_in[17];
    const float* tau     = (const float*)d_in[18];
    const float* ca_in_w = (const float*)d_in[19];
    const float* ca_in_b = (const float*)d_in[20];
    const float* ca_out_w= (const float*)d_in[21];
    const float* ca_out_b= (const float*)d_in[22];
    const float* ff_w1   = (const float*)d_in[23];
    const float* ff_b1   = (const float*)d_in[24];
    const float* ff_w2   = (const float*)d_in[25];
    const float* ff_b2   = (const float*)d_in[26];
    float* out = (float*)d_out;

    // workspace layout
    const size_t TOKC = (size_t)NTOK * CC;   // 12,845,056 floats
    float* ws    = (float*)d_ws;
    float* M0    = ws;                 // qkv[0:512] / proj / q2 / cout / ffhP / final
    float* M1    = ws + TOKC;          // qkv[512:1024] / coP / ffhP(cont.)
    float* M2    = ws + 2 * TOKC;      // qkv[1024:1536] / skipP (packed, persistent)
    float* kv2   = ws + 3 * TOKC;                 // [512][1024] fp32
    float* bias2 = kv2 + 524288;                  // [NH][64][64]
    short* SP    = (short*)(bias2 + 65536);
    size_t so = 0;
    short* vecP  = SP + so; so += 524288;   // [512][1024] packed (tm output)
    short* vecAP = SP + so; so += 262144;   // [512][512]  packed (vector input)
    short* tmP   = SP + so; so += 131072;   // [512][256]
    short* qkvP  = SP + so; so += 786432;   // [1536][512]
    short* wprP  = SP + so; so += 262144;   // [512][512]
    short* caiP  = SP + so; so += 786432;   // [1536][512]
    short* caoP  = SP + so; so += 262144;   // [512][512]
    short* ff1P  = SP + so; so += 1048576;  // [2048][512]
    short* ff2P  = SP + so; so += 1048576;  // [512][2048]

    float* dscrF = out;                // d_out as scratch (fp32 ff2)
    short* dscrS = (short*)out;        // d_out as scratch (packed tok/wout/pq)
    short* skipP = (short*)M2;
    short* coP   = (short*)M1;
    short* ffhP  = (short*)M0;         // spans M0+M1: [NTOK][2048] shorts

    // 0. weight planes (bf16 hi, transposed [N][K])
    hipLaunchKernelGGL(k_wtcvt, dim3(16, 8),  dim3(256), 0, stream, tm_w,    256,  512,  tmP);
    hipLaunchKernelGGL(k_wtcvt, dim3(48, 16), dim3(256), 0, stream, qkv_w,   512,  1536, qkvP);
    hipLaunchKernelGGL(k_wtcvt, dim3(16, 16), dim3(256), 0, stream, wproj_w, 512,  512,  wprP);
    hipLaunchKernelGGL(k_wtcvt, dim3(48, 16), dim3(256), 0, stream, ca_in_w, 512,  1536, caiP);
    hipLaunchKernelGGL(k_wtcvt, dim3(16, 16), dim3(256), 0, stream, ca_out_w,512,  512,  caoP);
    hipLaunchKernelGGL(k_wtcvt, dim3(64, 16), dim3(256), 0, stream, ff_w1,   512,  2048, ff1P);
    hipLaunchKernelGGL(k_wtcvt, dim3(16, 64), dim3(256), 0, stream, ff_w2,   2048, 512,  ff2P);
    hipLaunchKernelGGL(k_apack, dim3(512), dim3(256), 0, stream, vector, vecAP, 256);

    // 1. vec = gelu(vector @ tm_w + tm_b) -> packed vecP
    hipLaunchKernelGGL((k_mgemm2<1,0,1>), dim3(4, 4), dim3(256), 0, stream,
                       vecAP, 512, 256, tmP, 256, tm_b, (float*)nullptr, vecP, 512);
    // 2. tokP = gather(visual) -> d_out
    hipLaunchKernelGGL(k_gather_cm, dim3(NTOK), dim3(256), 0, stream, visual, dscrS);
    // 3. qkv = tok @ qkv_w + b  -> M0..M2 fp32
    hipLaunchKernelGGL((k_mgemm2<0,0,0>), dim3(12, 196), dim3(256), 0, stream,
                       dscrS, 1024, 512, qkvP, 512, qkv_b, M0, (short*)nullptr, 1536);
    // 4. relative-position bias (padded [NH][64][64])
    hipLaunchKernelGGL(k_meta, dim3(NH * 4096 / 256), dim3(256), 0, stream,
                       meta_w1, meta_b1, meta_w2, meta_b2, bias2);
    // 5. MFMA window attention -> packed wout -> d_out
    hipLaunchKernelGGL(k_winattn, dim3(BW, NH), dim3(256), 0, stream,
                       M0, bias2, tau, dscrS);
    // 6. proj = wout @ wproj_w + b -> M0 fp32
    hipLaunchKernelGGL((k_mgemm2<0,0,0>), dim3(4, 196), dim3(256), 0, stream,
                       dscrS, 1024, 512, wprP, 512, wproj_b, M0, (short*)nullptr, 512);
    // 7. skipP = pack(LN1(fold(proj)) + visual) -> M2
    hipLaunchKernelGGL(k_ln1_fold, dim3(NTOK), dim3(256), 0, stream,
                       M0, visual, ln1_g, ln1_b, skipP);
    // 8. pqP = gather(skipP) -> d_out
    hipLaunchKernelGGL(k_gather_win, dim3(NTOK), dim3(128), 0, stream, skipP, dscrS);
    // 9. q2 = pq @ ca_in_w[:, :512] + bq -> M0 fp32
    hipLaunchKernelGGL((k_mgemm2<0,0,0>), dim3(4, 196), dim3(256), 0, stream,
                       dscrS, 1024, 512, caiP, 512, ca_in_b, M0, (short*)nullptr, 512);
    // 10. kv2 = vec @ ca_in_w[:, 512:] + b[512:] -> fp32
    hipLaunchKernelGGL((k_mgemm2<0,0,0>), dim3(8, 4), dim3(256), 0, stream,
                       vecP, 1024, 512, caiP + (size_t)512 * 512, 512, ca_in_b + 512,
                       kv2, (short*)nullptr, 1024);
    // 11. MFMA cross attention -> packed co -> M1
    hipLaunchKernelGGL(k_crossattn, dim3(BW, NH), dim3(256), 0, stream,
                       M0, kv2, coP);
    // 12. cout = co @ ca_out_w + b -> M0 fp32
    hipLaunchKernelGGL((k_mgemm2<0,0,0>), dim3(4, 196), dim3(256), 0, stream,
                       coP, 1024, 512, caoP, 512, ca_out_b, M0, (short*)nullptr, 512);
    // 13. skipP += LN2(fold(cout))
    hipLaunchKernelGGL(k_ln2_fold_add, dim3(NTOK), dim3(256), 0, stream,
                       M0, ln2_g, ln2_b, skipP);
    // 14a. ffh_lo = gelu(skip @ ff_w1[:, :1024] + b1) -> packed -> M0M1
    hipLaunchKernelGGL((k_mgemm2<1,0,1>), dim3(8, 196), dim3(256), 0, stream,
                       skipP, 1024, 512, ff1P, 512, ff_b1, (float*)nullptr, (short*)ffhP, 1024);
    // 14b. ff2 = ffh_lo @ ff_w2[:1024, :] + b2 -> d_out fp32
    hipLaunchKernelGGL((k_mgemm2<0,0,0>), dim3(4, 196), dim3(256), 0, stream,
                       ffhP, 2048, 1024, ff2P, 2048, ff_b2, dscrF, (short*)nullptr, 512);
    // 14c. ffh_hi = gelu(skip @ ff_w1[:, 1024:] + b1[1024:]) -> packed -> M0M1
    hipLaunchKernelGGL((k_mgemm2<1,0,1>), dim3(8, 196), dim3(256), 0, stream,
                       skipP, 1024, 512, ff1P + (size_t)1024 * 512, 512, ff_b1 + 1024,
                       (float*)nullptr, (short*)ffhP, 1024);
    // 14d. ff2 += ffh_hi @ ff_w2[1024:, :]
    hipLaunchKernelGGL((k_mgemm2<0,1,0>), dim3(4, 196), dim3(256), 0, stream,
                       ffhP, 2048, 1024, ff2P + 1024, 2048, ff_b2, dscrF, (short*)nullptr, 512);
    // 15. final = skip + LN3(ff2) -> M0 fp32 (token-major)
    hipLaunchKernelGGL(k_ln3_final, dim3(NTOK), dim3(256), 0, stream,
                       dscrF, skipP, ln3_g, ln3_b, M0);
    // 16. final -> d_out (channel-major)
    hipLaunchKernelGGL(k_transpose_tm2cm, dim3(HWP / 32, CC / 32, BB), dim3(32, 8), 0, stream,
                       M0, out);
}

// Round 7
// 1080.747 us; speedup vs baseline: 3.5178x; 1.0783x over previous
//
#include <hip/hip_runtime.h>
#include <hip/hip_bf16.h>
#include <cstdint>

// ---------------- problem constants ----------------
#define BB   8
#define CC   512
#define HH   56
#define WW2  56
#define HWP  3136          // 56*56
#define WS   7
#define SS   3
#define NH   16
#define HD   32
#define TT   49            // WS*WS
#define NW   64            // (56/7)^2
#define LL   64
#define BW   512           // BB*NW
#define NTOK 25088         // BW*TT == BB*HWP

typedef __attribute__((ext_vector_type(8))) short bf16x8;
typedef __attribute__((ext_vector_type(4))) float f32x4;

// ---------------- helpers ----------------
__device__ __forceinline__ float gelu_exact(float x) {
    return 0.5f * x * (1.0f + erff(x * 0.70710678118654752440f));
}
__device__ __forceinline__ short f2bf(float v) {
    __hip_bfloat16 b = __float2bfloat16(v);
    return *reinterpret_cast<short*>(&b);
}
__device__ __forceinline__ float bf2f(short s) {
    __hip_bfloat16 b = *reinterpret_cast<__hip_bfloat16*>(&s);
    return __bfloat162float(b);
}
__device__ __forceinline__ void gl_lds16(const void* g, void* l) {
    __builtin_amdgcn_global_load_lds(
        (const __attribute__((address_space(1))) void*)g,
        (__attribute__((address_space(3))) void*)l, 16, 0, 0);
}

__device__ __forceinline__ float blk_sum256(float v, volatile float* red) {
    #pragma unroll
    for (int o = 32; o > 0; o >>= 1) v += __shfl_down(v, o, 64);
    int lane = threadIdx.x & 63, w = threadIdx.x >> 6;
    if (lane == 0) red[w] = v;
    __syncthreads();
    float s = red[0] + red[1] + red[2] + red[3];
    __syncthreads();
    return s;
}

// window row r -> flat pixel index under fold + roll(+3)
__device__ __forceinline__ int fold_pix(int r) {
    int bw = r / TT, t = r - bw * TT;
    int b = bw >> 6, nw = bw & 63;
    int wy = nw >> 3, wx = nw & 7;
    int ty = t / WS, tx = t - ty * WS;
    int hh = wy * WS + ty + SS; if (hh >= HH) hh -= HH;
    int ww = wx * WS + tx + SS; if (ww >= WW2) ww -= WW2;
    return b * HWP + hh * WW2 + ww;
}

__device__ __forceinline__ int region_of(int hh, int ww) {
    return (hh < 49 ? 0 : (hh < 53 ? 1 : 2)) * 3 + (ww < 49 ? 0 : (ww < 53 ? 1 : 2));
}

// ---------------- transpose: [B][HW][C] -> [B][C][HW] ----------------
__global__ __launch_bounds__(256) void k_transpose_tm2cm(const float* __restrict__ in,
                                                         float* __restrict__ out) {
    __shared__ float tile[32][33];
    int b = blockIdx.z;
    int hw0 = blockIdx.x * 32;
    int c0 = blockIdx.y * 32;
    const float* src = in + (size_t)b * CC * HWP;
    float* dst = out + (size_t)b * CC * HWP;
    for (int i = threadIdx.y; i < 32; i += 8)
        tile[i][threadIdx.x] = src[(size_t)(hw0 + i) * CC + c0 + threadIdx.x];
    __syncthreads();
    for (int i = threadIdx.y; i < 32; i += 8)
        dst[(size_t)(c0 + i) * HWP + hw0 + threadIdx.x] = tile[threadIdx.x][i];
}

// ---------------- weight convert: [K][N] fp32 -> [N][K] bf16 (hi only) ----------------
__global__ __launch_bounds__(256) void k_wtcvt(const float* __restrict__ W, int K, int N,
                                               short* __restrict__ out) {
    __shared__ float tile[32][33];
    int n0 = blockIdx.x * 32, k0 = blockIdx.y * 32;
    int tx = threadIdx.x & 31, ty = threadIdx.x >> 5;
    for (int i = ty; i < 32; i += 8)
        tile[i][tx] = W[(size_t)(k0 + i) * N + n0 + tx];
    __syncthreads();
    for (int i = ty; i < 32; i += 8)
        out[(size_t)(n0 + i) * K + k0 + tx] = f2bf(tile[tx][i]);
}

// ---------------- activation pack: [M][Kf] fp32 -> [M][2Kf] bf16 [hi|lo] ----------------
__global__ __launch_bounds__(256) void k_apack(const float* __restrict__ in,
                                               short* __restrict__ out, int Kf) {
    int m = blockIdx.x;
    for (int c = threadIdx.x; c < Kf; c += 256) {
        float v = in[(size_t)m * Kf + c];
        short h = f2bf(v);
        out[(size_t)m * 2 * Kf + c] = h;
        out[(size_t)m * 2 * Kf + Kf + c] = f2bf(v - bf2f(h));
    }
}

// ---------------- MFMA GEMM, packed-A [Ah|Al], bf16 weight plane B[N][ldk] ----------------
// 1D grid (nwg divisible by 8); XCD-aware swizzle so same-M-tile blocks share an XCD L2.
template<int ACT, int BETA, int PACK>
__global__ __launch_bounds__(256) void k_mgemm2(
    const short* __restrict__ A, int lda2, int K,
    const short* __restrict__ B, int ldk,
    const float* __restrict__ bias,
    float* __restrict__ Of, short* __restrict__ Os, int ldo, int nx)
{
    __shared__ short sAh[128 * 64];
    __shared__ short sAl[128 * 64];
    __shared__ short sB [128 * 64];
    int tid = threadIdx.x;
    int w = tid >> 6, lane = tid & 63;
    int wm = w >> 1, wn = w & 1;
    int lrow = lane & 15, kgrp = lane >> 4;

    // XCD-aware bijective swizzle (grid size divisible by 8)
    int nwg = gridDim.x;
    int orig = blockIdx.x;
    int wgid = (orig & 7) * (nwg >> 3) + (orig >> 3);
    int bx = wgid % nx, by = wgid / nx;
    int m0 = by * 128, n0 = bx * 128;

    int srow8 = lane >> 3;                 // 0..7 (row within 8-row region)
    int clog  = (lane & 7) ^ srow8;        // swizzled logical k-group for this lane

    f32x4 acc[4][4] = {};

    for (int k0 = 0; k0 < K; k0 += 64) {
        #pragma unroll
        for (int i = 0; i < 4; ++i) {
            int r = w * 4 + i;                 // wave-uniform region 0..15
            int row = r * 8 + srow8;
            const short* ga = A + (size_t)(m0 + row) * lda2 + k0 + clog * 8;
            const short* gb = B + (size_t)(n0 + row) * ldk  + k0 + clog * 8;
            gl_lds16(ga,     &sAh[r * 512]);
            gl_lds16(ga + K, &sAl[r * 512]);
            gl_lds16(gb,     &sB [r * 512]);
        }
        asm volatile("s_waitcnt vmcnt(0)" ::: "memory");
        __syncthreads();

        bf16x8 ah[4][2], al[4][2];
        #pragma unroll
        for (int mi = 0; mi < 4; ++mi) {
            int rr = wm * 64 + mi * 16 + lrow;
            int base = rr * 64, swz = rr & 7;
            #pragma unroll
            for (int ks = 0; ks < 2; ++ks) {
                int off = base + (((ks * 4 + kgrp) ^ swz) << 3);
                ah[mi][ks] = *(const bf16x8*)&sAh[off];
                al[mi][ks] = *(const bf16x8*)&sAl[off];
            }
        }
        #pragma unroll
        for (int ni = 0; ni < 4; ++ni) {
            int rr = wn * 64 + ni * 16 + lrow;
            int base = rr * 64, swz = rr & 7;
            bf16x8 bb0 = *(const bf16x8*)&sB[base + (((kgrp    ) ^ swz) << 3)];
            bf16x8 bb1 = *(const bf16x8*)&sB[base + (((kgrp + 4) ^ swz) << 3)];
            #pragma unroll
            for (int mi = 0; mi < 4; ++mi) {
                acc[mi][ni] = __builtin_amdgcn_mfma_f32_16x16x32_bf16(ah[mi][0], bb0, acc[mi][ni], 0, 0, 0);
                acc[mi][ni] = __builtin_amdgcn_mfma_f32_16x16x32_bf16(al[mi][0], bb0, acc[mi][ni], 0, 0, 0);
                acc[mi][ni] = __builtin_amdgcn_mfma_f32_16x16x32_bf16(ah[mi][1], bb1, acc[mi][ni], 0, 0, 0);
                acc[mi][ni] = __builtin_amdgcn_mfma_f32_16x16x32_bf16(al[mi][1], bb1, acc[mi][ni], 0, 0, 0);
            }
        }
        __syncthreads();
    }

    #pragma unroll
    for (int mi = 0; mi < 4; ++mi)
        #pragma unroll
        for (int ni = 0; ni < 4; ++ni) {
            int col = n0 + wn * 64 + ni * 16 + lrow;
            int rb  = m0 + wm * 64 + mi * 16 + kgrp * 4;
            float bv = (BETA == 0) ? bias[col] : 0.0f;
            #pragma unroll
            for (int r = 0; r < 4; ++r) {
                float v = acc[mi][ni][r];
                if (BETA) {
                    Of[(size_t)(rb + r) * ldo + col] += v;
                } else {
                    v += bv;
                    if (ACT) v = gelu_exact(v);
                    if (PACK) {
                        short h = f2bf(v);
                        size_t ob = (size_t)(rb + r) * (2 * ldo) + col;
                        Os[ob] = h;
                        Os[ob + ldo] = f2bf(v - bf2f(h));
                    } else {
                        Of[(size_t)(rb + r) * ldo + col] = v;
                    }
                }
            }
        }
}

// ---------------- window gather from channel-major visual -> packed bf16 ----------------
__global__ __launch_bounds__(256) void k_gather_cm(const float* __restrict__ vis,
                                                   short* __restrict__ dst) {
    int r = blockIdx.x;
    int p = fold_pix(r);
    int b = p / HWP, hw = p - b * HWP;
    const float* src = vis + (size_t)b * CC * HWP + hw;
    short* d = dst + (size_t)r * 1024;
    int c = threadIdx.x;
    float v0 = src[(size_t)c * HWP];
    float v1 = src[(size_t)(c + 256) * HWP];
    short h0 = f2bf(v0); d[c]       = h0; d[512 + c] = f2bf(v0 - bf2f(h0));
    short h1 = f2bf(v1); d[c + 256] = h1; d[768 + c] = f2bf(v1 - bf2f(h1));
}

// ---------------- window gather of packed rows (skip -> pq) ----------------
__global__ __launch_bounds__(128) void k_gather_win(const short* __restrict__ srcP,
                                                    short* __restrict__ dst) {
    int r = blockIdx.x;
    int p = fold_pix(r);
    const uint4* s4 = (const uint4*)(srcP + (size_t)p * 1024);
    uint4* d4 = (uint4*)(dst + (size_t)r * 1024);
    d4[threadIdx.x] = s4[threadIdx.x];
}

// ---------------- meta MLP bias -> padded bias2[h][64][64] ----------------
__global__ __launch_bounds__(256) void k_meta(const float* __restrict__ w1,
                                              const float* __restrict__ b1,
                                              const float* __restrict__ w2,
                                              const float* __restrict__ b2,
                                              float* __restrict__ bias2) {
    int id = blockIdx.x * 256 + threadIdx.x;   // NH*64*64
    int h = id >> 12, p = id & 4095;
    int i = p >> 6, j = p & 63;
    float val = 0.f;
    if (i < TT && j < TT) {
        float fy = (float)(i / WS - j / WS);
        float fx = (float)(i % WS - j % WS);
        float r0 = (fy > 0.f ? 1.f : (fy < 0.f ? -1.f : 0.f)) * log1pf(fabsf(fy));
        float r1 = (fx > 0.f ? 1.f : (fx < 0.f ? -1.f : 0.f)) * log1pf(fabsf(fx));
        float acc = 0.f;
        for (int m = 0; m < 256; ++m) {
            float hv = fmaxf(r0 * w1[m] + r1 * w1[256 + m] + b1[m], 0.f);
            acc += hv * w2[m * NH + h];
        }
        val = acc + b2[h];
    }
    bias2[id] = val;
}

// ---------------- MFMA window attention ----------------
__global__ __launch_bounds__(256) void k_winattn(const float* __restrict__ qkv,
                                                 const float* __restrict__ bias2,
                                                 const float* __restrict__ tau,
                                                 short* __restrict__ woutP) {
    __shared__ short Qh[64 * 40], Ql[64 * 40], Kh[64 * 40], Kl[64 * 40];
    __shared__ short Vt[32 * 72];
    __shared__ short P2[64 * 72];
    __shared__ float qn[64], kn[64];
    int bw = blockIdx.x, h = blockIdx.y;
    int tid = threadIdx.x;
    int wv = tid >> 6, lane = tid & 63;

    int d = tid & 31, t0 = tid >> 5;
    for (int t = t0; t < 64; t += 8) {
        float q = 0.f, k = 0.f, v = 0.f;
        if (t < TT) {
            size_t g = (size_t)(bw * TT + t) * 1536 + h * HD + d;
            q = qkv[g]; k = qkv[g + 512]; v = qkv[g + 1024];
        }
        short qh = f2bf(q); Qh[t * 40 + d] = qh; Ql[t * 40 + d] = f2bf(q - bf2f(qh));
        short kh = f2bf(k); Kh[t * 40 + d] = kh; Kl[t * 40 + d] = f2bf(k - bf2f(kh));
        Vt[d * 72 + t] = f2bf(v);
        float qq = q * q, kk = k * k;
        #pragma unroll
        for (int o = 16; o > 0; o >>= 1) {
            qq += __shfl_xor(qq, o, 64);
            kk += __shfl_xor(kk, o, 64);
        }
        if (d == 0) { qn[t] = sqrtf(qq); kn[t] = sqrtf(kk); }
    }
    __syncthreads();

    int lrow = lane & 15, kg = lane >> 4;
    int i = wv * 16 + lrow;

    bf16x8 qbh = *(const bf16x8*)&Qh[i * 40 + kg * 8];
    bf16x8 qbl = *(const bf16x8*)&Ql[i * 40 + kg * 8];
    f32x4 st[4];
    #pragma unroll
    for (int jt = 0; jt < 4; ++jt) {
        bf16x8 kah = *(const bf16x8*)&Kh[(jt * 16 + lrow) * 40 + kg * 8];
        bf16x8 kal = *(const bf16x8*)&Kl[(jt * 16 + lrow) * 40 + kg * 8];
        f32x4 c = {0.f, 0.f, 0.f, 0.f};
        c = __builtin_amdgcn_mfma_f32_16x16x32_bf16(kah, qbh, c, 0, 0, 0);
        c = __builtin_amdgcn_mfma_f32_16x16x32_bf16(kal, qbh, c, 0, 0, 0);
        c = __builtin_amdgcn_mfma_f32_16x16x32_bf16(kah, qbl, c, 0, 0, 0);
        st[jt] = c;
    }

    float inv_ts = 1.0f / fmaxf(tau[h], 0.01f);
    float qni = qn[i];
    int nw_ = bw & 63, wy = nw_ >> 3, wx = nw_ & 7;
    int ri = region_of(wy * WS + i / WS, wx * WS + i % WS);
    float av[4][4];
    float m = -1e30f;
    #pragma unroll
    for (int jt = 0; jt < 4; ++jt) {
        float4 bb = *(const float4*)&bias2[(size_t)h * 4096 + i * 64 + jt * 16 + kg * 4];
        const float* bbp = (const float*)&bb;
        #pragma unroll
        for (int r = 0; r < 4; ++r) {
            int j = jt * 16 + kg * 4 + r;
            float a = -1e30f;
            if (j < TT) {
                float den = fmaxf(qni * kn[j], 1e-6f);
                int rj = region_of(wy * WS + j / WS, wx * WS + j % WS);
                a = st[jt][r] / den * inv_ts + bbp[r];
                if (ri != rj) a -= 100.0f;
            }
            av[jt][r] = a;
            m = fmaxf(m, a);
        }
    }
    m = fmaxf(m, __shfl_xor(m, 16, 64));
    m = fmaxf(m, __shfl_xor(m, 32, 64));
    float s = 0.f;
    #pragma unroll
    for (int jt = 0; jt < 4; ++jt)
        #pragma unroll
        for (int r = 0; r < 4; ++r) {
            float e = expf(av[jt][r] - m);
            av[jt][r] = e; s += e;
        }
    s += __shfl_xor(s, 16, 64);
    s += __shfl_xor(s, 32, 64);
    float inv = 1.0f / s;
    #pragma unroll
    for (int jt = 0; jt < 4; ++jt) {
        short p4[4];
        #pragma unroll
        for (int r = 0; r < 4; ++r) p4[r] = f2bf(av[jt][r] * inv);
        *(uint2*)&P2[i * 72 + jt * 16 + kg * 4] = *(const uint2*)p4;
    }

    f32x4 o0 = {0.f, 0.f, 0.f, 0.f}, o1 = {0.f, 0.f, 0.f, 0.f};
    #pragma unroll
    for (int ks = 0; ks < 2; ++ks) {
        bf16x8 pb = *(const bf16x8*)&P2[i * 72 + ks * 32 + kg * 8];
        bf16x8 v0 = *(const bf16x8*)&Vt[lrow * 72 + ks * 32 + kg * 8];
        bf16x8 v1 = *(const bf16x8*)&Vt[(16 + lrow) * 72 + ks * 32 + kg * 8];
        o0 = __builtin_amdgcn_mfma_f32_16x16x32_bf16(v0, pb, o0, 0, 0, 0);
        o1 = __builtin_amdgcn_mfma_f32_16x16x32_bf16(v1, pb, o1, 0, 0, 0);
    }

    if (i < TT) {
        size_t ob = (size_t)(bw * TT + i) * 1024 + h * HD;
        #pragma unroll
        for (int r = 0; r < 4; ++r) {
            int d0 = kg * 4 + r;
            float va = o0[r], vb = o1[r];
            short ha = f2bf(va);
            woutP[ob + d0] = ha;
            woutP[ob + 512 + d0] = f2bf(va - bf2f(ha));
            short hb = f2bf(vb);
            woutP[ob + 16 + d0] = hb;
            woutP[ob + 512 + 16 + d0] = f2bf(vb - bf2f(hb));
        }
    }
}

// ---------------- MFMA cross attention (window bw attends to vec[bw % 8]) ----------------
__global__ __launch_bounds__(256) void k_crossattn(const float* __restrict__ q2,
                                                   const float* __restrict__ kv2,
                                                   short* __restrict__ coP) {
    __shared__ short Qh[64 * 40], Ql[64 * 40], Kh[64 * 40], Kl[64 * 40];
    __shared__ short Vt[32 * 72];
    __shared__ short P2[64 * 72];
    int bw = blockIdx.x, h = blockIdx.y;
    int bvec = bw & 7;
    int tid = threadIdx.x;
    int wv = tid >> 6, lane = tid & 63;

    int d = tid & 31, t0 = tid >> 5;
    for (int t = t0; t < 64; t += 8) {
        float q = 0.f;
        if (t < TT)
            q = q2[(size_t)(bw * TT + t) * CC + h * HD + d];
        size_t g = (size_t)(bvec * LL + t) * 1024 + h * HD + d;
        float k = kv2[g];
        float v = kv2[g + 512];
        short qh = f2bf(q); Qh[t * 40 + d] = qh; Ql[t * 40 + d] = f2bf(q - bf2f(qh));
        short kh = f2bf(k); Kh[t * 40 + d] = kh; Kl[t * 40 + d] = f2bf(k - bf2f(kh));
        Vt[d * 72 + t] = f2bf(v);
    }
    __syncthreads();

    int lrow = lane & 15, kg = lane >> 4;
    int i = wv * 16 + lrow;

    bf16x8 qbh = *(const bf16x8*)&Qh[i * 40 + kg * 8];
    bf16x8 qbl = *(const bf16x8*)&Ql[i * 40 + kg * 8];
    f32x4 st[4];
    #pragma unroll
    for (int jt = 0; jt < 4; ++jt) {
        bf16x8 kah = *(const bf16x8*)&Kh[(jt * 16 + lrow) * 40 + kg * 8];
        bf16x8 kal = *(const bf16x8*)&Kl[(jt * 16 + lrow) * 40 + kg * 8];
        f32x4 c = {0.f, 0.f, 0.f, 0.f};
        c = __builtin_amdgcn_mfma_f32_16x16x32_bf16(kah, qbh, c, 0, 0, 0);
        c = __builtin_amdgcn_mfma_f32_16x16x32_bf16(kal, qbh, c, 0, 0, 0);
        c = __builtin_amdgcn_mfma_f32_16x16x32_bf16(kah, qbl, c, 0, 0, 0);
        st[jt] = c;
    }

    const float scale = 0.17677669529663687f;  // 32^-0.5
    float av[4][4];
    float m = -1e30f;
    #pragma unroll
    for (int jt = 0; jt < 4; ++jt)
        #pragma unroll
        for (int r = 0; r < 4; ++r) {
            float a = st[jt][r] * scale;
            av[jt][r] = a;
            m = fmaxf(m, a);
        }
    m = fmaxf(m, __shfl_xor(m, 16, 64));
    m = fmaxf(m, __shfl_xor(m, 32, 64));
    float s = 0.f;
    #pragma unroll
    for (int jt = 0; jt < 4; ++jt)
        #pragma unroll
        for (int r = 0; r < 4; ++r) {
            float e = expf(av[jt][r] - m);
            av[jt][r] = e; s += e;
        }
    s += __shfl_xor(s, 16, 64);
    s += __shfl_xor(s, 32, 64);
    float inv = 1.0f / s;
    #pragma unroll
    for (int jt = 0; jt < 4; ++jt) {
        short p4[4];
        #pragma unroll
        for (int r = 0; r < 4; ++r) p4[r] = f2bf(av[jt][r] * inv);
        *(uint2*)&P2[i * 72 + jt * 16 + kg * 4] = *(const uint2*)p4;
    }

    f32x4 o0 = {0.f, 0.f, 0.f, 0.f}, o1 = {0.f, 0.f, 0.f, 0.f};
    #pragma unroll
    for (int ks = 0; ks < 2; ++ks) {
        bf16x8 pb = *(const bf16x8*)&P2[i * 72 + ks * 32 + kg * 8];
        bf16x8 v0 = *(const bf16x8*)&Vt[lrow * 72 + ks * 32 + kg * 8];
        bf16x8 v1 = *(const bf16x8*)&Vt[(16 + lrow) * 72 + ks * 32 + kg * 8];
        o0 = __builtin_amdgcn_mfma_f32_16x16x32_bf16(v0, pb, o0, 0, 0, 0);
        o1 = __builtin_amdgcn_mfma_f32_16x16x32_bf16(v1, pb, o1, 0, 0, 0);
    }

    if (i < TT) {
        size_t ob = (size_t)(bw * TT + i) * 1024 + h * HD;
        #pragma unroll
        for (int r = 0; r < 4; ++r) {
            int d0 = kg * 4 + r;
            float va = o0[r], vb = o1[r];
            short ha = f2bf(va);
            coP[ob + d0] = ha;
            coP[ob + 512 + d0] = f2bf(va - bf2f(ha));
            short hb = f2bf(vb);
            coP[ob + 16 + d0] = hb;
            coP[ob + 512 + 16 + d0] = f2bf(vb - bf2f(hb));
        }
    }
}

// ---------------- skip = LN1(fold(proj)) + visual  -> packed skip ----------------
__global__ __launch_bounds__(256) void k_ln1_fold(const float* __restrict__ proj,
                                                  const float* __restrict__ vis,
                                                  const float* __restrict__ g,
                                                  const float* __restrict__ bta,
                                                  short* __restrict__ skipP) {
    __shared__ float red[4];
    int r = blockIdx.x;
    int p = fold_pix(r);
    int b = p / HWP, hw = p - b * HWP;
    const float* row = proj + (size_t)r * CC;
    int c0 = threadIdx.x, c1 = threadIdx.x + 256;
    float x0 = row[c0], x1 = row[c1];
    float mu = blk_sum256(x0 + x1, red) * (1.f / CC);
    float d0 = x0 - mu, d1 = x1 - mu;
    float var = blk_sum256(d0 * d0 + d1 * d1, red) * (1.f / CC);
    float rstd = rsqrtf(var + 1e-5f);
    const float* vb = vis + (size_t)b * CC * HWP + hw;
    float y0 = d0 * rstd * g[c0] + bta[c0] + vb[(size_t)c0 * HWP];
    float y1 = d1 * rstd * g[c1] + bta[c1] + vb[(size_t)c1 * HWP];
    size_t o = (size_t)p * 1024;
    short h0 = f2bf(y0); skipP[o + c0] = h0; skipP[o + 512 + c0] = f2bf(y0 - bf2f(h0));
    short h1 = f2bf(y1); skipP[o + c1] = h1; skipP[o + 512 + c1] = f2bf(y1 - bf2f(h1));
}

// ---------------- skip += LN2(fold(cout))  (packed RMW) ----------------
__global__ __launch_bounds__(256) void k_ln2_fold_add(const float* __restrict__ cout_,
                                                      const float* __restrict__ g,
                                                      const float* __restrict__ bta,
                                                      short* __restrict__ skipP) {
    __shared__ float red[4];
    int r = blockIdx.x;
    int p = fold_pix(r);
    const float* row = cout_ + (size_t)r * CC;
    int c0 = threadIdx.x, c1 = threadIdx.x + 256;
    float x0 = row[c0], x1 = row[c1];
    float mu = blk_sum256(x0 + x1, red) * (1.f / CC);
    float d0 = x0 - mu, d1 = x1 - mu;
    float var = blk_sum256(d0 * d0 + d1 * d1, red) * (1.f / CC);
    float rstd = rsqrtf(var + 1e-5f);
    size_t o = (size_t)p * 1024;
    float s0 = bf2f(skipP[o + c0]) + bf2f(skipP[o + 512 + c0]);
    float s1 = bf2f(skipP[o + c1]) + bf2f(skipP[o + 512 + c1]);
    float y0 = s0 + d0 * rstd * g[c0] + bta[c0];
    float y1 = s1 + d1 * rstd * g[c1] + bta[c1];
    short h0 = f2bf(y0); skipP[o + c0] = h0; skipP[o + 512 + c0] = f2bf(y0 - bf2f(h0));
    short h1 = f2bf(y1); skipP[o + c1] = h1; skipP[o + 512 + c1] = f2bf(y1 - bf2f(h1));
}

// ---------------- final = skip + LN3(ff2) ----------------
__global__ __launch_bounds__(256) void k_ln3_final(const float* __restrict__ ff2,
                                                   const short* __restrict__ skipP,
                                                   const float* __restrict__ g,
                                                   const float* __restrict__ bta,
                                                   float* __restrict__ fin) {
    __shared__ float red[4];
    size_t p = blockIdx.x;
    const float* row = ff2 + p * CC;
    int c0 = threadIdx.x, c1 = threadIdx.x + 256;
    float x0 = row[c0], x1 = row[c1];
    float mu = blk_sum256(x0 + x1, red) * (1.f / CC);
    float d0 = x0 - mu, d1 = x1 - mu;
    float var = blk_sum256(d0 * d0 + d1 * d1, red) * (1.f / CC);
    float rstd = rsqrtf(var + 1e-5f);
    size_t o = p * 1024;
    float s0 = bf2f(skipP[o + c0]) + bf2f(skipP[o + 512 + c0]);
    float s1 = bf2f(skipP[o + c1]) + bf2f(skipP[o + 512 + c1]);
    fin[p * CC + c0] = s0 + d0 * rstd * g[c0] + bta[c0];
    fin[p * CC + c1] = s1 + d1 * rstd * g[c1] + bta[c1];
}

// ---------------- host launch ----------------
extern "C" void kernel_launch(void* const* d_in, const int* in_sizes, int n_in,
                              void* d_out, int out_size, void* d_ws, size_t ws_size,
                              hipStream_t stream) {
    const float* visual  = (const float*)d_in[0];
    const float* vector  = (const float*)d_in[1];
    const float* tm_w    = (const float*)d_in[2];
    const float* tm_b    = (const float*)d_in[3];
    const float* ln1_g   = (const float*)d_in[4];
    const float* ln1_b   = (const float*)d_in[5];
    const float* ln2_g   = (const float*)d_in[6];
    const float* ln2_b   = (const float*)d_in[7];
    const float* ln3_g   = (const float*)d_in[8];
    const float* ln3_b   = (const float*)d_in[9];
    const float* qkv_w   = (const float*)d_in[10];
    const float* qkv_b   = (const float*)d_in[11];
    const float* wproj_w = (const float*)d_in[12];
    const float* wproj_b = (const float*)d_in[13];
    const float* meta_w1 = (const float*)d_in[14];
    const float* meta_b1 = (const float*)d_in[15];
    const float* meta_w2 = (const float*)d_in[16];
    const float* meta_b2 = (const float*)d_in[17];
    const float* tau     = (const float*)d_in[18];
    const float* ca_in_w = (const float*)d_in[19];
    const float* ca_in_b = (const float*)d_in[20];
    const float* ca_out_w= (const float*)d_in[21];
    const float* ca_out_b= (const float*)d_in[22];
    const float* ff_w1   = (const float*)d_in[23];
    const float* ff_b1   = (const float*)d_in[24];
    const float* ff_w2   = (const float*)d_in[25];
    const float* ff_b2   = (const float*)d_in[26];
    float* out = (float*)d_out;

    // workspace layout
    const size_t TOKC = (size_t)NTOK * CC;   // 12,845,056 floats
    float* ws    = (float*)d_ws;
    float* M0    = ws;                 // qkv[0:512] / proj / q2 / cout / ffhP / final
    float* M1    = ws + TOKC;          // qkv[512:1024] / coP / ffhP(cont.)
    float* M2    = ws + 2 * TOKC;      // qkv[1024:1536] / skipP (packed, persistent)
    float* kv2   = ws + 3 * TOKC;                 // [512][1024] fp32
    float* bias2 = kv2 + 524288;                  // [NH][64][64]
    short* SP    = (short*)(bias2 + 65536);
    size_t so = 0;
    short* vecP  = SP + so; so += 524288;   // [512][1024] packed (tm output)
    short* vecAP = SP + so; so += 262144;   // [512][512]  packed (vector input)
    short* tmP   = SP + so; so += 131072;   // [512][256]
    short* qkvP  = SP + so; so += 786432;   // [1536][512]
    short* wprP  = SP + so; so += 262144;   // [512][512]
    short* caiP  = SP + so; so += 786432;   // [1536][512]
    short* caoP  = SP + so; so += 262144;   // [512][512]
    short* ff1P  = SP + so; so += 1048576;  // [2048][512]
    short* ff2P  = SP + so; so += 1048576;  // [512][2048]

    float* dscrF = out;                // d_out as scratch (fp32 ff2)
    short* dscrS = (short*)out;        // d_out as scratch (packed tok/wout/pq)
    short* skipP = (short*)M2;
    short* coP   = (short*)M1;
    short* ffhP  = (short*)M0;         // spans M0+M1: [NTOK][2048] shorts

    // 0. weight planes (bf16 hi, transposed [N][K])
    hipLaunchKernelGGL(k_wtcvt, dim3(16, 8),  dim3(256), 0, stream, tm_w,    256,  512,  tmP);
    hipLaunchKernelGGL(k_wtcvt, dim3(48, 16), dim3(256), 0, stream, qkv_w,   512,  1536, qkvP);
    hipLaunchKernelGGL(k_wtcvt, dim3(16, 16), dim3(256), 0, stream, wproj_w, 512,  512,  wprP);
    hipLaunchKernelGGL(k_wtcvt, dim3(48, 16), dim3(256), 0, stream, ca_in_w, 512,  1536, caiP);
    hipLaunchKernelGGL(k_wtcvt, dim3(16, 16), dim3(256), 0, stream, ca_out_w,512,  512,  caoP);
    hipLaunchKernelGGL(k_wtcvt, dim3(64, 16), dim3(256), 0, stream, ff_w1,   512,  2048, ff1P);
    hipLaunchKernelGGL(k_wtcvt, dim3(16, 64), dim3(256), 0, stream, ff_w2,   2048, 512,  ff2P);
    hipLaunchKernelGGL(k_apack, dim3(512), dim3(256), 0, stream, vector, vecAP, 256);

    // 1. vec = gelu(vector @ tm_w + tm_b) -> packed vecP   grid 4x4=16
    hipLaunchKernelGGL((k_mgemm2<1,0,1>), dim3(16), dim3(256), 0, stream,
                       vecAP, 512, 256, tmP, 256, tm_b, (float*)nullptr, vecP, 512, 4);
    // 2. tokP = gather(visual) -> d_out
    hipLaunchKernelGGL(k_gather_cm, dim3(NTOK), dim3(256), 0, stream, visual, dscrS);
    // 3. qkv = tok @ qkv_w + b  -> M0..M2 fp32   grid 12x196=2352
    hipLaunchKernelGGL((k_mgemm2<0,0,0>), dim3(2352), dim3(256), 0, stream,
                       dscrS, 1024, 512, qkvP, 512, qkv_b, M0, (short*)nullptr, 1536, 12);
    // 4. relative-position bias (padded [NH][64][64])
    hipLaunchKernelGGL(k_meta, dim3(NH * 4096 / 256), dim3(256), 0, stream,
                       meta_w1, meta_b1, meta_w2, meta_b2, bias2);
    // 5. MFMA window attention -> packed wout -> d_out
    hipLaunchKernelGGL(k_winattn, dim3(BW, NH), dim3(256), 0, stream,
                       M0, bias2, tau, dscrS);
    // 6. proj = wout @ wproj_w + b -> M0 fp32   grid 4x196=784
    hipLaunchKernelGGL((k_mgemm2<0,0,0>), dim3(784), dim3(256), 0, stream,
                       dscrS, 1024, 512, wprP, 512, wproj_b, M0, (short*)nullptr, 512, 4);
    // 7. skipP = pack(LN1(fold(proj)) + visual) -> M2
    hipLaunchKernelGGL(k_ln1_fold, dim3(NTOK), dim3(256), 0, stream,
                       M0, visual, ln1_g, ln1_b, skipP);
    // 8. pqP = gather(skipP) -> d_out
    hipLaunchKernelGGL(k_gather_win, dim3(NTOK), dim3(128), 0, stream, skipP, dscrS);
    // 9. q2 = pq @ ca_in_w[:, :512] + bq -> M0 fp32   grid 784
    hipLaunchKernelGGL((k_mgemm2<0,0,0>), dim3(784), dim3(256), 0, stream,
                       dscrS, 1024, 512, caiP, 512, ca_in_b, M0, (short*)nullptr, 512, 4);
    // 10. kv2 = vec @ ca_in_w[:, 512:] + b[512:] -> fp32   grid 8x4=32
    hipLaunchKernelGGL((k_mgemm2<0,0,0>), dim3(32), dim3(256), 0, stream,
                       vecP, 1024, 512, caiP + (size_t)512 * 512, 512, ca_in_b + 512,
                       kv2, (short*)nullptr, 1024, 8);
    // 11. MFMA cross attention -> packed co -> M1
    hipLaunchKernelGGL(k_crossattn, dim3(BW, NH), dim3(256), 0, stream,
                       M0, kv2, coP);
    // 12. cout = co @ ca_out_w + b -> M0 fp32   grid 784
    hipLaunchKernelGGL((k_mgemm2<0,0,0>), dim3(784), dim3(256), 0, stream,
                       coP, 1024, 512, caoP, 512, ca_out_b, M0, (short*)nullptr, 512, 4);
    // 13. skipP += LN2(fold(cout))
    hipLaunchKernelGGL(k_ln2_fold_add, dim3(NTOK), dim3(256), 0, stream,
                       M0, ln2_g, ln2_b, skipP);
    // 14a. ffh_lo = gelu(skip @ ff_w1[:, :1024] + b1) -> packed -> M0M1   grid 8x196=1568
    hipLaunchKernelGGL((k_mgemm2<1,0,1>), dim3(1568), dim3(256), 0, stream,
                       skipP, 1024, 512, ff1P, 512, ff_b1, (float*)nullptr, (short*)ffhP, 1024, 8);
    // 14b. ff2 = ffh_lo @ ff_w2[:1024, :] + b2 -> d_out fp32   grid 784
    hipLaunchKernelGGL((k_mgemm2<0,0,0>), dim3(784), dim3(256), 0, stream,
                       ffhP, 2048, 1024, ff2P, 2048, ff_b2, dscrF, (short*)nullptr, 512, 4);
    // 14c. ffh_hi = gelu(skip @ ff_w1[:, 1024:] + b1[1024:]) -> packed -> M0M1   grid 1568
    hipLaunchKernelGGL((k_mgemm2<1,0,1>), dim3(1568), dim3(256), 0, stream,
                       skipP, 1024, 512, ff1P + (size_t)1024 * 512, 512, ff_b1 + 1024,
                       (float*)nullptr, (short*)ffhP, 1024, 8);
    // 14d. ff2 += ffh_hi @ ff_w2[1024:, :]   grid 784
    hipLaunchKernelGGL((k_mgemm2<0,1,0>), dim3(784), dim3(256), 0, stream,
                       ffhP, 2048, 1024, ff2P + 1024, 2048, ff_b2, dscrF, (short*)nullptr, 512, 4);
    // 15. final = skip + LN3(ff2) -> M0 fp32 (token-major)
    hipLaunchKernelGGL(k_ln3_final, dim3(NTOK), dim3(256), 0, stream,
                       dscrF, skipP, ln3_g, ln3_b, M0);
    // 16. final -> d_out (channel-major)
    hipLaunchKernelGGL(k_transpose_tm2cm, dim3(HWP / 32, CC / 32, BB), dim3(32, 8), 0, stream,
                       M0, out);
}